// Round 1
// baseline (7199.566 us; speedup 1.0000x reference)
//
#include <hip/hip_runtime.h>
#include <math.h>

// ---- problem constants ----
#define BB    2
#define CC    96
#define NHD   4
#define HDIM  24
#define LAT_  181
#define LON_  360
#define PT_   2
#define HH    186      // LAT + 2 + 3
#define WWID  360
#define WH_   6
#define WW_   12
#define NTOK  72       // WH*WW
#define SH_   3
#define SW_   6
#define NWH_  31
#define NWW_  30
#define NWIN  930
#define SCALE_ 0.20412414523193154f   // 24^-0.5

// ---------------- pad + NCHW->NHWC ----------------
__global__ void k_pad(const float* __restrict__ in, float* __restrict__ X) {
    long id = (long)blockIdx.x * 256 + threadIdx.x;
    const long total = (long)BB * HH * WWID * CC;
    if (id >= total) return;
    int c = (int)(id % CC);
    long t = id / CC;
    int w = (int)(t % WWID); t /= WWID;
    int h = (int)(t % HH);
    int b = (int)(t / HH);
    int lat = h - PT_;
    float v = 0.f;
    if (lat >= 0 && lat < LAT_)
        v = in[(((long)b * CC + c) * LAT_ + lat) * LON_ + w];
    X[id] = v;
}

// ---------------- LayerNorm over C=96, one wave per token ----------------
__global__ __launch_bounds__(256) void k_ln(const float* __restrict__ X, float* __restrict__ Y,
                                            const float* __restrict__ g, const float* __restrict__ bta) {
    int tok = blockIdx.x * 4 + (threadIdx.x >> 6);
    int lane = threadIdx.x & 63;
    const float* xp = X + (long)tok * CC;
    float v0 = xp[lane];
    float v1 = (lane < 32) ? xp[64 + lane] : 0.f;
    float s = v0 + v1, sq = v0 * v0 + v1 * v1;
    for (int off = 32; off; off >>= 1) {
        s  += __shfl_down(s, off);
        sq += __shfl_down(sq, off);
    }
    s = __shfl(s, 0); sq = __shfl(sq, 0);
    float mean = s * (1.f / CC);
    float var = sq * (1.f / CC) - mean * mean;
    float rs = rsqrtf(var + 1e-5f);
    float* yp = Y + (long)tok * CC;
    yp[lane] = (v0 - mean) * rs * g[lane] + bta[lane];
    if (lane < 32) yp[64 + lane] = (v1 - mean) * rs * g[64 + lane] + bta[64 + lane];
}

// region label for the shift mask, from rolled global coords
__device__ __forceinline__ int regionOf(int hr, int wr) {
    int rh = hr < (HH - WH_) ? 0 : (hr < (HH - SH_) ? 1 : 2);
    int rw = wr < (WWID - WW_) ? 0 : (wr < (WWID - SW_) ? 1 : 2);
    return rh * 3 + rw;
}

// ---------------- fused window attention: qkv -> attn -> proj -> residual ----------------
template <int SHIFT>
__global__ __launch_bounds__(256) void k_attn(const float* __restrict__ Y, float* __restrict__ X,
                                              const float* __restrict__ qkvw, const float* __restrict__ qkvb,
                                              const float* __restrict__ projw, const float* __restrict__ projb,
                                              const float* __restrict__ rpb) {
    __shared__ float yw[NTOK * CC];          // window input; reused as attention output
    __shared__ float qkvs[NTOK * 3 * CC];    // q|k|v per token
    int bid = blockIdx.x;
    int b = bid / NWIN, wi = bid % NWIN;
    int nwh = wi / NWW_, nww = wi % NWW_;
    int tid = threadIdx.x;

    // phase 0: gather window (shift roll folded into source index)
    for (int idx = tid; idx < NTOK * CC; idx += 256) {
        int t = idx / CC, c = idx % CC;
        int th = t / WW_, tw = t % WW_;
        int hr = nwh * WH_ + th, wr = nww * WW_ + tw;
        int ho = SHIFT ? (hr + SH_) % HH : hr;
        int wo = SHIFT ? (wr + SW_) % WWID : wr;
        yw[idx] = Y[(((long)b * HH + ho) * WWID + wo) * CC + c];
    }
    __syncthreads();

    // phase 1: qkv = yw @ qkvw.T + qkvb
    for (int idx = tid; idx < NTOK * 3 * CC; idx += 256) {
        int t = idx / (3 * CC), o = idx % (3 * CC);
        const float* wrow = qkvw + (long)o * CC;
        const float* yrow = yw + t * CC;
        float sum = qkvb[o];
        #pragma unroll
        for (int c = 0; c < CC; ++c) sum += yrow[c] * wrow[c];
        qkvs[t * (3 * CC) + o] = sum;
    }
    __syncthreads();

    // phase 2: per (head,row) attention; output overwrites yw
    for (int r = tid; r < NHD * NTOK; r += 256) {
        int h = r / NTOK, i = r % NTOK;
        float qr[HDIM];
        const float* qp = qkvs + i * (3 * CC) + h * HDIM;
        #pragma unroll
        for (int d = 0; d < HDIM; ++d) qr[d] = qp[d] * SCALE_;
        int thi = i / WW_, twi = i % WW_;
        int regi = 0;
        if (SHIFT) regi = regionOf(nwh * WH_ + thi, nww * WW_ + twi);

        // pass A: row max
        float m = -1e30f;
        for (int j = 0; j < NTOK; ++j) {
            const float* kp = qkvs + j * (3 * CC) + CC + h * HDIM;
            float sv = 0.f;
            #pragma unroll
            for (int d = 0; d < HDIM; ++d) sv += qr[d] * kp[d];
            int thj = j / WW_, twj = j % WW_;
            int ridx = (thi - thj + WH_ - 1) * (2 * WW_ - 1) + (twi - twj + WW_ - 1);
            sv += rpb[ridx * NHD + h];
            if (SHIFT) {
                if (regi != regionOf(nwh * WH_ + thj, nww * WW_ + twj)) sv -= 100.f;
            }
            m = fmaxf(m, sv);
        }
        // pass B: exp-sum + PV accumulate
        float sum = 0.f;
        float acc[HDIM];
        #pragma unroll
        for (int d = 0; d < HDIM; ++d) acc[d] = 0.f;
        for (int j = 0; j < NTOK; ++j) {
            const float* kp = qkvs + j * (3 * CC) + CC + h * HDIM;
            float sv = 0.f;
            #pragma unroll
            for (int d = 0; d < HDIM; ++d) sv += qr[d] * kp[d];
            int thj = j / WW_, twj = j % WW_;
            int ridx = (thi - thj + WH_ - 1) * (2 * WW_ - 1) + (twi - twj + WW_ - 1);
            sv += rpb[ridx * NHD + h];
            if (SHIFT) {
                if (regi != regionOf(nwh * WH_ + thj, nww * WW_ + twj)) sv -= 100.f;
            }
            float p = expf(sv - m);
            sum += p;
            const float* vp = qkvs + j * (3 * CC) + 2 * CC + h * HDIM;
            #pragma unroll
            for (int d = 0; d < HDIM; ++d) acc[d] += p * vp[d];
        }
        float inv = 1.f / sum;
        float* op = yw + i * CC + h * HDIM;
        #pragma unroll
        for (int d = 0; d < HDIM; ++d) op[d] = acc[d] * inv;
    }
    __syncthreads();

    // phase 3: proj + residual scatter (unroll folded into dest index)
    for (int idx = tid; idx < NTOK * CC; idx += 256) {
        int t = idx / CC, co = idx % CC;
        const float* wrow = projw + (long)co * CC;
        const float* arow = yw + t * CC;
        float sum = projb[co];
        #pragma unroll
        for (int c = 0; c < CC; ++c) sum += arow[c] * wrow[c];
        int th = t / WW_, tw = t % WW_;
        int hr = nwh * WH_ + th, wr = nww * WW_ + tw;
        int ho = SHIFT ? (hr + SH_) % HH : hr;
        int wo = SHIFT ? (wr + SW_) % WWID : wr;
        X[(((long)b * HH + ho) * WWID + wo) * CC + co] += sum;
    }
}

// ---------------- fused MLP: reads ln2 from Y, X += fc2(gelu(fc1(ln2))) ----------------
#define MT 8   // tokens per block
__global__ __launch_bounds__(128) void k_mlp(const float* __restrict__ Y, float* __restrict__ X,
                                             const float* __restrict__ w1, const float* __restrict__ b1v,
                                             const float* __restrict__ w2, const float* __restrict__ b2v) {
    __shared__ float yt[MT * CC];
    __shared__ float hb[MT * 4 * CC];
    long tok0 = (long)blockIdx.x * MT;
    int tid = threadIdx.x;

    for (int idx = tid; idx < MT * CC; idx += 128)
        yt[idx] = Y[tok0 * CC + idx];
    __syncthreads();

    // hidden: 384 rows, weight row reused across MT tokens
    for (int o = tid; o < 4 * CC; o += 128) {
        const float* wrow = w1 + (long)o * CC;
        float acc[MT];
        float bb = b1v[o];
        #pragma unroll
        for (int t = 0; t < MT; ++t) acc[t] = bb;
        for (int c = 0; c < CC; ++c) {
            float w = wrow[c];
            #pragma unroll
            for (int t = 0; t < MT; ++t) acc[t] += yt[t * CC + c] * w;
        }
        #pragma unroll
        for (int t = 0; t < MT; ++t) {
            float s = acc[t];
            float u = tanhf(0.7978845608028654f * (s + 0.044715f * s * s * s));
            hb[t * (4 * CC) + o] = 0.5f * s * (1.f + u);
        }
    }
    __syncthreads();

    // out: 96 cols, weight row reused across MT tokens
    if (tid < CC) {
        const float* wrow = w2 + (long)tid * (4 * CC);
        float acc[MT];
        float bb = b2v[tid];
        #pragma unroll
        for (int t = 0; t < MT; ++t) acc[t] = bb;
        for (int c = 0; c < 4 * CC; ++c) {
            float w = wrow[c];
            #pragma unroll
            for (int t = 0; t < MT; ++t) acc[t] += hb[t * (4 * CC) + c] * w;
        }
        #pragma unroll
        for (int t = 0; t < MT; ++t)
            X[(tok0 + t) * CC + tid] += acc[t];
    }
}

// ---------------- crop + NHWC->NCHW ----------------
__global__ void k_crop(const float* __restrict__ X, float* __restrict__ out) {
    long id = (long)blockIdx.x * 256 + threadIdx.x;
    const long total = (long)BB * CC * LAT_ * LON_;
    if (id >= total) return;
    int w = (int)(id % LON_);
    long t = id / LON_;
    int lat = (int)(t % LAT_); t /= LAT_;
    int c = (int)(t % CC);
    int b = (int)(t / CC);
    out[id] = X[(((long)b * HH + (lat + PT_)) * WWID + w) * CC + c];
}

extern "C" void kernel_launch(void* const* d_in, const int* in_sizes, int n_in,
                              void* d_out, int out_size, void* d_ws, size_t ws_size,
                              hipStream_t stream) {
    const float* x     = (const float*)d_in[0];
    const float* g1    = (const float*)d_in[1];
    const float* b1    = (const float*)d_in[2];
    const float* qkvw  = (const float*)d_in[3];
    const float* qkvb  = (const float*)d_in[4];
    const float* projw = (const float*)d_in[5];
    const float* projb = (const float*)d_in[6];
    const float* rpb   = (const float*)d_in[7];
    const float* g2    = (const float*)d_in[8];
    const float* b2    = (const float*)d_in[9];
    const float* f1w   = (const float*)d_in[10];
    const float* f1b   = (const float*)d_in[11];
    const float* f2w   = (const float*)d_in[12];
    const float* f2b   = (const float*)d_in[13];

    float* X = (float*)d_ws;                            // (B,H,W,C)  51.4 MB
    float* Y = X + (long)BB * HH * WWID * CC;           // LN scratch 51.4 MB

    const long padtot = (long)BB * HH * WWID * CC;
    const int ntok = BB * HH * WWID;                    // 133920

    k_pad<<<(int)((padtot + 255) / 256), 256, 0, stream>>>(x, X);

    for (int i = 0; i < 2; ++i) {
        k_ln<<<ntok / 4, 256, 0, stream>>>(X, Y, g1 + i * CC, b1 + i * CC);
        if (i == 0) {
            k_attn<0><<<BB * NWIN, 256, 0, stream>>>(Y, X,
                qkvw + (long)i * 3 * CC * CC, qkvb + (long)i * 3 * CC,
                projw + (long)i * CC * CC, projb + (long)i * CC,
                rpb + (long)i * 253 * NHD);
        } else {
            k_attn<1><<<BB * NWIN, 256, 0, stream>>>(Y, X,
                qkvw + (long)i * 3 * CC * CC, qkvb + (long)i * 3 * CC,
                projw + (long)i * CC * CC, projb + (long)i * CC,
                rpb + (long)i * 253 * NHD);
        }
        k_ln<<<ntok / 4, 256, 0, stream>>>(X, Y, g2 + i * CC, b2 + i * CC);
        k_mlp<<<ntok / MT, 128, 0, stream>>>(Y, X,
            f1w + (long)i * 4 * CC * CC, f1b + (long)i * 4 * CC,
            f2w + (long)i * CC * 4 * CC, f2b + (long)i * CC);
    }

    const long croptot = (long)BB * CC * LAT_ * LON_;
    k_crop<<<(int)((croptot + 255) / 256), 256, 0, stream>>>(X, (float*)d_out);
}

// Round 2
// 2659.022 us; speedup vs baseline: 2.7076x; 2.7076x over previous
//
#include <hip/hip_runtime.h>
#include <math.h>

// ---- problem constants ----
#define BB    2
#define CC    96
#define NHD   4
#define HDIM  24
#define LAT_  181
#define LON_  360
#define PT_   2
#define HH    186
#define WWID  360
#define WH_   6
#define WW_   12
#define NTOK  72
#define SH_   3
#define SW_   6
#define NWH_  31
#define NWW_  30
#define NWIN  930
#define SCALE_ 0.20412414523193154f   // 24^-0.5
#define ATHREADS 576                  // 9 waves

// bf16 helpers (bit-level)
__device__ __forceinline__ unsigned short pk_bf16(float x) {
    unsigned u = __float_as_uint(x);
    unsigned r = (u + 0x7fffu + ((u >> 16) & 1u)) >> 16;   // RNE
    return (unsigned short)r;
}
__device__ __forceinline__ float bf_lo(unsigned u) { return __uint_as_float(u << 16); }
__device__ __forceinline__ float bf_hi(unsigned u) { return __uint_as_float(u & 0xffff0000u); }

// ---------------- pad + NCHW->NHWC ----------------
__global__ void k_pad(const float* __restrict__ in, float* __restrict__ X) {
    long id = (long)blockIdx.x * 256 + threadIdx.x;
    const long total = (long)BB * HH * WWID * CC;
    if (id >= total) return;
    int c = (int)(id % CC);
    long t = id / CC;
    int w = (int)(t % WWID); t /= WWID;
    int h = (int)(t % HH);
    int b = (int)(t / HH);
    int lat = h - PT_;
    float v = 0.f;
    if (lat >= 0 && lat < LAT_)
        v = in[(((long)b * CC + c) * LAT_ + lat) * LON_ + w];
    X[id] = v;
}

// ---------------- LayerNorm over C=96, one wave per token ----------------
__global__ __launch_bounds__(256) void k_ln(const float* __restrict__ X, float* __restrict__ Y,
                                            const float* __restrict__ g, const float* __restrict__ bta) {
    int tok = blockIdx.x * 4 + (threadIdx.x >> 6);
    int lane = threadIdx.x & 63;
    const float* xp = X + (long)tok * CC;
    float v0 = xp[lane];
    float v1 = (lane < 32) ? xp[64 + lane] : 0.f;
    float s = v0 + v1, sq = v0 * v0 + v1 * v1;
    for (int off = 32; off; off >>= 1) {
        s  += __shfl_down(s, off);
        sq += __shfl_down(sq, off);
    }
    s = __shfl(s, 0); sq = __shfl(sq, 0);
    float mean = s * (1.f / CC);
    float var = sq * (1.f / CC) - mean * mean;
    float rs = rsqrtf(var + 1e-5f);
    float* yp = Y + (long)tok * CC;
    yp[lane] = (v0 - mean) * rs * g[lane] + bta[lane];
    if (lane < 32) yp[64 + lane] = (v1 - mean) * rs * g[64 + lane] + bta[64 + lane];
}

__device__ __forceinline__ int regionOf(int hr, int wr) {
    int rh = hr < (HH - WH_) ? 0 : (hr < (HH - SH_) ? 1 : 2);
    int rw = wr < (WWID - WW_) ? 0 : (wr < (WWID - SW_) ? 1 : 2);
    return rh * 3 + rw;
}

// ---------------- fused window attention ----------------
// LDS layout (69248 B -> 2 blocks/CU):
//   [0, 27648)        ysT   f32 [96][72]  (phase 0-1 input; reused as osT bf16 [96][72] in phase 2-3)
//   [27648, 41472)    qs    bf16 [4][72][24]  (pre-scaled by SCALE_)
//   [41472, 55296)    ks    bf16 [4][72][24]
//   [55296, 69120)    vs    bf16 [4][72][24]
//   [69120, 69192)    regj  u8 [72]
template <int SHIFT>
__global__ __launch_bounds__(ATHREADS, 5) void k_attn(const float* __restrict__ Y, float* __restrict__ X,
                                              const float* __restrict__ qkvw, const float* __restrict__ qkvb,
                                              const float* __restrict__ projw, const float* __restrict__ projb,
                                              const float* __restrict__ rpb) {
    __shared__ __align__(16) unsigned char smem[69248];
    float* ysT = (float*)smem;                                    // [96][72]
    unsigned short* osT = (unsigned short*)smem;                  // [96][72] bf16 (reuse)
    unsigned short* qs = (unsigned short*)(smem + 27648);
    unsigned short* ks = (unsigned short*)(smem + 41472);
    unsigned short* vs = (unsigned short*)(smem + 55296);
    unsigned char* regj = smem + 69120;

    int bid = blockIdx.x;
    int b = bid / NWIN, wi = bid % NWIN;
    int nwh = wi / NWW_, nww = wi % NWW_;
    int tid = threadIdx.x;

    // ---- phase 0: gather window (roll folded), transpose into ysT ----
    for (int idx = tid; idx < NTOK * CC; idx += ATHREADS) {
        int t = idx / CC, c = idx % CC;
        int th = t / WW_, tw = t % WW_;
        int hr = nwh * WH_ + th, wr = nww * WW_ + tw;
        int ho = SHIFT ? (hr + SH_) % HH : hr;
        int wo = SHIFT ? (wr + SW_) % WWID : wr;
        ysT[c * NTOK + t] = Y[(((long)b * HH + ho) * WWID + wo) * CC + c];
    }
    if (SHIFT && tid < NTOK) {
        int th = tid / WW_, tw = tid % WW_;
        regj[tid] = (unsigned char)regionOf(nwh * WH_ + th, nww * WW_ + tw);
    }
    __syncthreads();

    // ---- phase 1: qkv GEMM, 8-token tiles (2592 items) ----
    for (int item = tid; item < 288 * 9; item += ATHREADS) {
        int o = item % 288;
        int t0 = (item / 288) * 8;
        const float* wrow = qkvw + o * CC;
        float bv = qkvb[o];
        float acc[8];
        #pragma unroll
        for (int k = 0; k < 8; ++k) acc[k] = bv;
        for (int c = 0; c < CC; ++c) {
            float w = wrow[c];
            const float* yp = ysT + c * NTOK + t0;
            float4 y0 = *(const float4*)yp;
            float4 y1 = *(const float4*)(yp + 4);
            acc[0] += w * y0.x; acc[1] += w * y0.y; acc[2] += w * y0.z; acc[3] += w * y0.w;
            acc[4] += w * y1.x; acc[5] += w * y1.y; acc[6] += w * y1.z; acc[7] += w * y1.w;
        }
        int which = o / CC;          // 0=q 1=k 2=v
        int oo = o % CC;
        int h = oo / HDIM, d = oo % HDIM;
        unsigned short* dst = (which == 0) ? qs : (which == 1 ? ks : vs);
        float scale = (which == 0) ? SCALE_ : 1.f;
        #pragma unroll
        for (int k = 0; k < 8; ++k)
            dst[(h * NTOK + t0 + k) * HDIM + d] = pk_bf16(acc[k] * scale);
    }
    __syncthreads();

    // ---- phase 2: attention, 2 threads per (head,row), single-pass softmax ----
    {
        int u = tid;                 // 576 units exactly
        int row = u >> 1, half = u & 1;
        int h = row / NTOK, i = row % NTOK;
        int thi = i / WW_, twi = i % WW_;
        int cbias = (thi + WH_ - 1) * (2 * WW_ - 1) + (twi + WW_ - 1);
        int regi = SHIFT ? (int)regj[i] : 0;

        float q[HDIM];
        const unsigned* qp = (const unsigned*)(qs + (h * NTOK + i) * HDIM);
        #pragma unroll
        for (int dd = 0; dd < 12; ++dd) {
            unsigned uu = qp[dd];
            q[2 * dd] = bf_lo(uu); q[2 * dd + 1] = bf_hi(uu);
        }
        float acc[HDIM];
        #pragma unroll
        for (int d = 0; d < HDIM; ++d) acc[d] = 0.f;
        float sum = 0.f;

        int jbeg = half * 36, jend = jbeg + 36;
        for (int j = jbeg; j < jend; ++j) {
            const unsigned* kp = (const unsigned*)(ks + (h * NTOK + j) * HDIM);
            float sv0 = 0.f, sv1 = 0.f;
            #pragma unroll
            for (int dd = 0; dd < 12; ++dd) {
                unsigned uu = kp[dd];
                sv0 += q[2 * dd] * bf_lo(uu);
                sv1 += q[2 * dd + 1] * bf_hi(uu);
            }
            int thj = j / WW_, twj = j % WW_;
            float sv = sv0 + sv1 + rpb[(cbias - thj * (2 * WW_ - 1) - twj) * NHD + h];
            if (SHIFT) { if ((int)regj[j] != regi) sv -= 100.f; }
            float p = __expf(sv);
            sum += p;
            const unsigned* vp = (const unsigned*)(vs + (h * NTOK + j) * HDIM);
            #pragma unroll
            for (int dd = 0; dd < 12; ++dd) {
                unsigned uu = vp[dd];
                acc[2 * dd]     += p * bf_lo(uu);
                acc[2 * dd + 1] += p * bf_hi(uu);
            }
        }
        // merge j-halves (adjacent lanes)
        sum += __shfl_xor(sum, 1);
        #pragma unroll
        for (int d = 0; d < HDIM; ++d) acc[d] += __shfl_xor(acc[d], 1);
        __syncthreads();             // ysT fully consumed; safe to overwrite as osT
        if (half == 0) {
            float inv = 1.f / sum;
            #pragma unroll
            for (int d = 0; d < HDIM; ++d)
                osT[(h * HDIM + d) * NTOK + i] = pk_bf16(acc[d] * inv);
        }
    }
    __syncthreads();

    // ---- phase 3: proj + residual scatter, 8-token tiles (864 items) ----
    for (int item = tid; item < CC * 9; item += ATHREADS) {
        int o = item % CC;
        int t0 = (item / CC) * 8;
        const float* wrow = projw + o * CC;
        float bv = projb[o];
        float acc[8];
        #pragma unroll
        for (int k = 0; k < 8; ++k) acc[k] = bv;
        for (int c = 0; c < CC; ++c) {
            float w = wrow[c];
            const unsigned* op2 = (const unsigned*)(osT + c * NTOK + t0);
            #pragma unroll
            for (int dd = 0; dd < 4; ++dd) {
                unsigned uu = op2[dd];
                acc[2 * dd]     += w * bf_lo(uu);
                acc[2 * dd + 1] += w * bf_hi(uu);
            }
        }
        #pragma unroll
        for (int k = 0; k < 8; ++k) {
            int t = t0 + k;
            int th = t / WW_, tw = t % WW_;
            int hr = nwh * WH_ + th, wr = nww * WW_ + tw;
            int ho = SHIFT ? (hr + SH_) % HH : hr;
            int wo = SHIFT ? (wr + SW_) % WWID : wr;
            X[(((long)b * HH + ho) * WWID + wo) * CC + o] += acc[k];
        }
    }
}

// ---------------- fused MLP ----------------
#define MT 8
__global__ __launch_bounds__(128) void k_mlp(const float* __restrict__ Y, float* __restrict__ X,
                                             const float* __restrict__ w1, const float* __restrict__ b1v,
                                             const float* __restrict__ w2, const float* __restrict__ b2v) {
    __shared__ float yt[MT * CC];
    __shared__ float hb[MT * 4 * CC];
    long tok0 = (long)blockIdx.x * MT;
    int tid = threadIdx.x;

    for (int idx = tid; idx < MT * CC; idx += 128)
        yt[idx] = Y[tok0 * CC + idx];
    __syncthreads();

    for (int o = tid; o < 4 * CC; o += 128) {
        const float* wrow = w1 + (long)o * CC;
        float acc[MT];
        float bb = b1v[o];
        #pragma unroll
        for (int t = 0; t < MT; ++t) acc[t] = bb;
        for (int c = 0; c < CC; ++c) {
            float w = wrow[c];
            #pragma unroll
            for (int t = 0; t < MT; ++t) acc[t] += yt[t * CC + c] * w;
        }
        #pragma unroll
        for (int t = 0; t < MT; ++t) {
            float s = acc[t];
            float u = tanhf(0.7978845608028654f * (s + 0.044715f * s * s * s));
            hb[t * (4 * CC) + o] = 0.5f * s * (1.f + u);
        }
    }
    __syncthreads();

    if (tid < CC) {
        const float* wrow = w2 + (long)tid * (4 * CC);
        float acc[MT];
        float bb = b2v[tid];
        #pragma unroll
        for (int t = 0; t < MT; ++t) acc[t] = bb;
        for (int c = 0; c < 4 * CC; ++c) {
            float w = wrow[c];
            #pragma unroll
            for (int t = 0; t < MT; ++t) acc[t] += hb[t * (4 * CC) + c] * w;
        }
        #pragma unroll
        for (int t = 0; t < MT; ++t)
            X[(tok0 + t) * CC + tid] += acc[t];
    }
}

// ---------------- crop + NHWC->NCHW ----------------
__global__ void k_crop(const float* __restrict__ X, float* __restrict__ out) {
    long id = (long)blockIdx.x * 256 + threadIdx.x;
    const long total = (long)BB * CC * LAT_ * LON_;
    if (id >= total) return;
    int w = (int)(id % LON_);
    long t = id / LON_;
    int lat = (int)(t % LAT_); t /= LAT_;
    int c = (int)(t % CC);
    int b = (int)(t / CC);
    out[id] = X[(((long)b * HH + (lat + PT_)) * WWID + w) * CC + c];
}

extern "C" void kernel_launch(void* const* d_in, const int* in_sizes, int n_in,
                              void* d_out, int out_size, void* d_ws, size_t ws_size,
                              hipStream_t stream) {
    const float* x     = (const float*)d_in[0];
    const float* g1    = (const float*)d_in[1];
    const float* b1    = (const float*)d_in[2];
    const float* qkvw  = (const float*)d_in[3];
    const float* qkvb  = (const float*)d_in[4];
    const float* projw = (const float*)d_in[5];
    const float* projb = (const float*)d_in[6];
    const float* rpb   = (const float*)d_in[7];
    const float* g2    = (const float*)d_in[8];
    const float* b2    = (const float*)d_in[9];
    const float* f1w   = (const float*)d_in[10];
    const float* f1b   = (const float*)d_in[11];
    const float* f2w   = (const float*)d_in[12];
    const float* f2b   = (const float*)d_in[13];

    float* X = (float*)d_ws;
    float* Y = X + (long)BB * HH * WWID * CC;

    const long padtot = (long)BB * HH * WWID * CC;
    const int ntok = BB * HH * WWID;

    k_pad<<<(int)((padtot + 255) / 256), 256, 0, stream>>>(x, X);

    for (int i = 0; i < 2; ++i) {
        k_ln<<<ntok / 4, 256, 0, stream>>>(X, Y, g1 + i * CC, b1 + i * CC);
        if (i == 0) {
            k_attn<0><<<BB * NWIN, ATHREADS, 0, stream>>>(Y, X,
                qkvw + (long)i * 3 * CC * CC, qkvb + (long)i * 3 * CC,
                projw + (long)i * CC * CC, projb + (long)i * CC,
                rpb + (long)i * 253 * NHD);
        } else {
            k_attn<1><<<BB * NWIN, ATHREADS, 0, stream>>>(Y, X,
                qkvw + (long)i * 3 * CC * CC, qkvb + (long)i * 3 * CC,
                projw + (long)i * CC * CC, projb + (long)i * CC,
                rpb + (long)i * 253 * NHD);
        }
        k_ln<<<ntok / 4, 256, 0, stream>>>(X, Y, g2 + i * CC, b2 + i * CC);
        k_mlp<<<ntok / MT, 128, 0, stream>>>(Y, X,
            f1w + (long)i * 4 * CC * CC, f1b + (long)i * 4 * CC,
            f2w + (long)i * CC * 4 * CC, f2b + (long)i * CC);
    }

    const long croptot = (long)BB * CC * LAT_ * LON_;
    k_crop<<<(int)((croptot + 255) / 256), 256, 0, stream>>>(X, (float*)d_out);
}

// Round 3
// 1524.848 us; speedup vs baseline: 4.7215x; 1.7438x over previous
//
#include <hip/hip_runtime.h>
#include <math.h>

// ---- problem constants ----
#define BB    2
#define CC    96
#define NHD   4
#define HDIM  24
#define LAT_  181
#define LON_  360
#define PT_   2
#define HH    186
#define WWID  360
#define WH_   6
#define WW_   12
#define NTOK  72
#define SH_   3
#define SW_   6
#define NWH_  31
#define NWW_  30
#define NWIN  930
#define SCALE_ 0.20412414523193154f   // 24^-0.5
#define ATHREADS 576                  // 9 waves

typedef __attribute__((ext_vector_type(8))) short short8v;
typedef __attribute__((ext_vector_type(4))) float f32x4;

// bf16 helpers (bit-level)
__device__ __forceinline__ unsigned short pk_bf16(float x) {
    unsigned u = __float_as_uint(x);
    unsigned r = (u + 0x7fffu + ((u >> 16) & 1u)) >> 16;   // RNE
    return (unsigned short)r;
}
__device__ __forceinline__ float bf_lo(unsigned u) { return __uint_as_float(u << 16); }
__device__ __forceinline__ float bf_hi(unsigned u) { return __uint_as_float(u & 0xffff0000u); }

// ---------------- pad + NCHW->NHWC ----------------
__global__ void k_pad(const float* __restrict__ in, float* __restrict__ X) {
    long id = (long)blockIdx.x * 256 + threadIdx.x;
    const long total = (long)BB * HH * WWID * CC;
    if (id >= total) return;
    int c = (int)(id % CC);
    long t = id / CC;
    int w = (int)(t % WWID); t /= WWID;
    int h = (int)(t % HH);
    int b = (int)(t / HH);
    int lat = h - PT_;
    float v = 0.f;
    if (lat >= 0 && lat < LAT_)
        v = in[(((long)b * CC + c) * LAT_ + lat) * LON_ + w];
    X[id] = v;
}

// ---------------- LayerNorm over C=96, one wave per token (used for ln1) ----------------
__global__ __launch_bounds__(256) void k_ln(const float* __restrict__ X, float* __restrict__ Y,
                                            const float* __restrict__ g, const float* __restrict__ bta) {
    int tok = blockIdx.x * 4 + (threadIdx.x >> 6);
    int lane = threadIdx.x & 63;
    const float* xp = X + (long)tok * CC;
    float v0 = xp[lane];
    float v1 = (lane < 32) ? xp[64 + lane] : 0.f;
    float s = v0 + v1, sq = v0 * v0 + v1 * v1;
    for (int off = 32; off; off >>= 1) {
        s  += __shfl_down(s, off);
        sq += __shfl_down(sq, off);
    }
    s = __shfl(s, 0); sq = __shfl(sq, 0);
    float mean = s * (1.f / CC);
    float var = sq * (1.f / CC) - mean * mean;
    float rs = rsqrtf(var + 1e-5f);
    float* yp = Y + (long)tok * CC;
    yp[lane] = (v0 - mean) * rs * g[lane] + bta[lane];
    if (lane < 32) yp[64 + lane] = (v1 - mean) * rs * g[64 + lane] + bta[64 + lane];
}

__device__ __forceinline__ int regionOf(int hr, int wr) {
    int rh = hr < (HH - WH_) ? 0 : (hr < (HH - SH_) ? 1 : 2);
    int rw = wr < (WWID - WW_) ? 0 : (wr < (WWID - SW_) ? 1 : 2);
    return rh * 3 + rw;
}

// ---------------- fused window attention (unchanged from R2) ----------------
template <int SHIFT>
__global__ __launch_bounds__(ATHREADS, 5) void k_attn(const float* __restrict__ Y, float* __restrict__ X,
                                              const float* __restrict__ qkvw, const float* __restrict__ qkvb,
                                              const float* __restrict__ projw, const float* __restrict__ projb,
                                              const float* __restrict__ rpb) {
    __shared__ __align__(16) unsigned char smem[69248];
    float* ysT = (float*)smem;                                    // [96][72]
    unsigned short* osT = (unsigned short*)smem;                  // [96][72] bf16 (reuse)
    unsigned short* qs = (unsigned short*)(smem + 27648);
    unsigned short* ks = (unsigned short*)(smem + 41472);
    unsigned short* vs = (unsigned short*)(smem + 55296);
    unsigned char* regj = smem + 69120;

    int bid = blockIdx.x;
    int b = bid / NWIN, wi = bid % NWIN;
    int nwh = wi / NWW_, nww = wi % NWW_;
    int tid = threadIdx.x;

    for (int idx = tid; idx < NTOK * CC; idx += ATHREADS) {
        int t = idx / CC, c = idx % CC;
        int th = t / WW_, tw = t % WW_;
        int hr = nwh * WH_ + th, wr = nww * WW_ + tw;
        int ho = SHIFT ? (hr + SH_) % HH : hr;
        int wo = SHIFT ? (wr + SW_) % WWID : wr;
        ysT[c * NTOK + t] = Y[(((long)b * HH + ho) * WWID + wo) * CC + c];
    }
    if (SHIFT && tid < NTOK) {
        int th = tid / WW_, tw = tid % WW_;
        regj[tid] = (unsigned char)regionOf(nwh * WH_ + th, nww * WW_ + tw);
    }
    __syncthreads();

    for (int item = tid; item < 288 * 9; item += ATHREADS) {
        int o = item % 288;
        int t0 = (item / 288) * 8;
        const float* wrow = qkvw + o * CC;
        float bv = qkvb[o];
        float acc[8];
        #pragma unroll
        for (int k = 0; k < 8; ++k) acc[k] = bv;
        for (int c = 0; c < CC; ++c) {
            float w = wrow[c];
            const float* yp = ysT + c * NTOK + t0;
            float4 y0 = *(const float4*)yp;
            float4 y1 = *(const float4*)(yp + 4);
            acc[0] += w * y0.x; acc[1] += w * y0.y; acc[2] += w * y0.z; acc[3] += w * y0.w;
            acc[4] += w * y1.x; acc[5] += w * y1.y; acc[6] += w * y1.z; acc[7] += w * y1.w;
        }
        int which = o / CC;
        int oo = o % CC;
        int h = oo / HDIM, d = oo % HDIM;
        unsigned short* dst = (which == 0) ? qs : (which == 1 ? ks : vs);
        float scale = (which == 0) ? SCALE_ : 1.f;
        #pragma unroll
        for (int k = 0; k < 8; ++k)
            dst[(h * NTOK + t0 + k) * HDIM + d] = pk_bf16(acc[k] * scale);
    }
    __syncthreads();

    {
        int u = tid;
        int row = u >> 1, half = u & 1;
        int h = row / NTOK, i = row % NTOK;
        int thi = i / WW_, twi = i % WW_;
        int cbias = (thi + WH_ - 1) * (2 * WW_ - 1) + (twi + WW_ - 1);
        int regi = SHIFT ? (int)regj[i] : 0;

        float q[HDIM];
        const unsigned* qp = (const unsigned*)(qs + (h * NTOK + i) * HDIM);
        #pragma unroll
        for (int dd = 0; dd < 12; ++dd) {
            unsigned uu = qp[dd];
            q[2 * dd] = bf_lo(uu); q[2 * dd + 1] = bf_hi(uu);
        }
        float acc[HDIM];
        #pragma unroll
        for (int d = 0; d < HDIM; ++d) acc[d] = 0.f;
        float sum = 0.f;

        int jbeg = half * 36, jend = jbeg + 36;
        for (int j = jbeg; j < jend; ++j) {
            const unsigned* kp = (const unsigned*)(ks + (h * NTOK + j) * HDIM);
            float sv0 = 0.f, sv1 = 0.f;
            #pragma unroll
            for (int dd = 0; dd < 12; ++dd) {
                unsigned uu = kp[dd];
                sv0 += q[2 * dd] * bf_lo(uu);
                sv1 += q[2 * dd + 1] * bf_hi(uu);
            }
            int thj = j / WW_, twj = j % WW_;
            float sv = sv0 + sv1 + rpb[(cbias - thj * (2 * WW_ - 1) - twj) * NHD + h];
            if (SHIFT) { if ((int)regj[j] != regi) sv -= 100.f; }
            float p = __expf(sv);
            sum += p;
            const unsigned* vp = (const unsigned*)(vs + (h * NTOK + j) * HDIM);
            #pragma unroll
            for (int dd = 0; dd < 12; ++dd) {
                unsigned uu = vp[dd];
                acc[2 * dd]     += p * bf_lo(uu);
                acc[2 * dd + 1] += p * bf_hi(uu);
            }
        }
        sum += __shfl_xor(sum, 1);
        #pragma unroll
        for (int d = 0; d < HDIM; ++d) acc[d] += __shfl_xor(acc[d], 1);
        __syncthreads();
        if (half == 0) {
            float inv = 1.f / sum;
            #pragma unroll
            for (int d = 0; d < HDIM; ++d)
                osT[(h * HDIM + d) * NTOK + i] = pk_bf16(acc[d] * inv);
        }
    }
    __syncthreads();

    for (int item = tid; item < CC * 9; item += ATHREADS) {
        int o = item % CC;
        int t0 = (item / CC) * 8;
        const float* wrow = projw + o * CC;
        float bv = projb[o];
        float acc[8];
        #pragma unroll
        for (int k = 0; k < 8; ++k) acc[k] = bv;
        for (int c = 0; c < CC; ++c) {
            float w = wrow[c];
            const unsigned* op2 = (const unsigned*)(osT + c * NTOK + t0);
            #pragma unroll
            for (int dd = 0; dd < 4; ++dd) {
                unsigned uu = op2[dd];
                acc[2 * dd]     += w * bf_lo(uu);
                acc[2 * dd + 1] += w * bf_hi(uu);
            }
        }
        #pragma unroll
        for (int k = 0; k < 8; ++k) {
            int t = t0 + k;
            int th = t / WW_, tw = t % WW_;
            int hr = nwh * WH_ + th, wr = nww * WW_ + tw;
            int ho = SHIFT ? (hr + SH_) % HH : hr;
            int wo = SHIFT ? (wr + SW_) % WWID : wr;
            X[(((long)b * HH + ho) * WWID + wo) * CC + o] += acc[k];
        }
    }
}

// ---------------- weight prep: fragment-ordered bf16 for MLP ----------------
// layout: w1f[layer][ks<3][nt<24][lane<64][e<8]; w2f[layer][ks<12][nt<6][lane<64][e<8]
__global__ void k_wprep(const float* __restrict__ f1w, const float* __restrict__ f2w,
                        unsigned short* __restrict__ wbf) {
    int id = blockIdx.x * 256 + threadIdx.x;   // 147456 total
    if (id < 73728) {
        int layer = id / 36864, rem = id % 36864;
        int ks = rem / 12288, r2 = rem % 12288;
        int nt = r2 / 512, r3 = r2 % 512;
        int lane = r3 / 8, e = r3 % 8;
        int o = nt * 16 + (lane & 15);
        int c = ks * 32 + 8 * (lane >> 4) + e;
        wbf[(long)layer * 36864 + rem] = pk_bf16(f1w[((long)layer * 384 + o) * 96 + c]);
    } else {
        int id2 = id - 73728;
        int layer = id2 / 36864, rem = id2 % 36864;
        int ks = rem / 3072, r2 = rem % 3072;
        int nt = r2 / 512, r3 = r2 % 512;
        int lane = r3 / 8, e = r3 % 8;
        int o = nt * 16 + (lane & 15);
        int c = ks * 32 + 8 * (lane >> 4) + e;
        wbf[73728 + (long)layer * 36864 + rem] = pk_bf16(f2w[((long)layer * 96 + o) * 384 + c]);
    }
}

// ---------------- fused LN2 + MFMA MLP: X += fc2(gelu(fc1(ln(X)))) ----------------
// 32 tokens/block, 256 threads = 4 waves.
__global__ __launch_bounds__(256, 4) void k_mlp_mfma(float* __restrict__ X,
        const float* __restrict__ g, const float* __restrict__ bta,
        const unsigned short* __restrict__ w1f, const float* __restrict__ b1v,
        const unsigned short* __restrict__ w2f, const float* __restrict__ b2v) {
    __shared__ __align__(16) unsigned short As[32 * 120];   // ln-out bf16, stride 120
    __shared__ __align__(16) unsigned short Hs[32 * 392];   // hidden bf16, stride 392
    long tok0 = (long)blockIdx.x * 32;
    int tid = threadIdx.x;

    // ---- stage + LayerNorm (8 threads per token) ----
    {
        int t = tid >> 3, p = tid & 7;
        const float* xr = X + (tok0 + t) * CC;
        float4 a = *(const float4*)(xr + p * 4);
        float4 b = *(const float4*)(xr + p * 4 + 32);
        float4 c4 = *(const float4*)(xr + p * 4 + 64);
        float s  = a.x + a.y + a.z + a.w + b.x + b.y + b.z + b.w + c4.x + c4.y + c4.z + c4.w;
        float sq = a.x*a.x + a.y*a.y + a.z*a.z + a.w*a.w + b.x*b.x + b.y*b.y + b.z*b.z + b.w*b.w
                 + c4.x*c4.x + c4.y*c4.y + c4.z*c4.z + c4.w*c4.w;
        #pragma unroll
        for (int off = 1; off < 8; off <<= 1) {
            s  += __shfl_xor(s, off);
            sq += __shfl_xor(sq, off);
        }
        float mean = s * (1.f / CC);
        float var = sq * (1.f / CC) - mean * mean;
        float rs = rsqrtf(var + 1e-5f);
        float4 g0 = *(const float4*)(g + p * 4);
        float4 g1 = *(const float4*)(g + p * 4 + 32);
        float4 g2 = *(const float4*)(g + p * 4 + 64);
        float4 t0 = *(const float4*)(bta + p * 4);
        float4 t1 = *(const float4*)(bta + p * 4 + 32);
        float4 t2 = *(const float4*)(bta + p * 4 + 64);
        unsigned short* arow = As + t * 120;
        arow[p*4+0]  = pk_bf16((a.x - mean) * rs * g0.x + t0.x);
        arow[p*4+1]  = pk_bf16((a.y - mean) * rs * g0.y + t0.y);
        arow[p*4+2]  = pk_bf16((a.z - mean) * rs * g0.z + t0.z);
        arow[p*4+3]  = pk_bf16((a.w - mean) * rs * g0.w + t0.w);
        arow[p*4+32] = pk_bf16((b.x - mean) * rs * g1.x + t1.x);
        arow[p*4+33] = pk_bf16((b.y - mean) * rs * g1.y + t1.y);
        arow[p*4+34] = pk_bf16((b.z - mean) * rs * g1.z + t1.z);
        arow[p*4+35] = pk_bf16((b.w - mean) * rs * g1.w + t1.w);
        arow[p*4+64] = pk_bf16((c4.x - mean) * rs * g2.x + t2.x);
        arow[p*4+65] = pk_bf16((c4.y - mean) * rs * g2.y + t2.y);
        arow[p*4+66] = pk_bf16((c4.z - mean) * rs * g2.z + t2.z);
        arow[p*4+67] = pk_bf16((c4.w - mean) * rs * g2.w + t2.w);
    }
    __syncthreads();

    int w = tid >> 6, lane = tid & 63;
    int wm = w & 1;
    int row = wm * 16 + (lane & 15);
    int kbase = 8 * (lane >> 4);

    // ---- fc1: M=32 N=384 K=96 ----
    {
        int wnh = w >> 1;                      // N-half (192 cols)
        short8v afr[3];
        #pragma unroll
        for (int ks = 0; ks < 3; ++ks)
            afr[ks] = *(const short8v*)(As + row * 120 + ks * 32 + kbase);
        f32x4 acc[12];
        #pragma unroll
        for (int j = 0; j < 12; ++j) acc[j] = (f32x4){0.f, 0.f, 0.f, 0.f};
        const short8v* wb = (const short8v*)w1f;
        #pragma unroll
        for (int j = 0; j < 12; ++j) {
            int nt = wnh * 12 + j;
            #pragma unroll
            for (int ks = 0; ks < 3; ++ks) {
                short8v bfr = wb[(ks * 24 + nt) * 64 + lane];
                acc[j] = __builtin_amdgcn_mfma_f32_16x16x32_bf16(afr[ks], bfr, acc[j], 0, 0, 0);
            }
        }
        #pragma unroll
        for (int j = 0; j < 12; ++j) {
            int n = (wnh * 12 + j) * 16 + (lane & 15);
            float bb = b1v[n];
            #pragma unroll
            for (int r = 0; r < 4; ++r) {
                float s = acc[j][r] + bb;
                float z = s + 0.044715f * s * s * s;
                float gl = s / (1.f + __expf(-1.5957691216057308f * z));
                Hs[(wm * 16 + 4 * (lane >> 4) + r) * 392 + n] = pk_bf16(gl);
            }
        }
    }
    __syncthreads();

    // ---- fc2: M=32 N=96 K=384 + residual ----
    {
        int wnt0 = (w >> 1) * 3;
        f32x4 acc2[3];
        #pragma unroll
        for (int j = 0; j < 3; ++j) acc2[j] = (f32x4){0.f, 0.f, 0.f, 0.f};
        const short8v* wb2 = (const short8v*)w2f;
        #pragma unroll
        for (int ks = 0; ks < 12; ++ks) {
            short8v a2 = *(const short8v*)(Hs + row * 392 + ks * 32 + kbase);
            #pragma unroll
            for (int j = 0; j < 3; ++j) {
                short8v bfr = wb2[(ks * 6 + wnt0 + j) * 64 + lane];
                acc2[j] = __builtin_amdgcn_mfma_f32_16x16x32_bf16(a2, bfr, acc2[j], 0, 0, 0);
            }
        }
        #pragma unroll
        for (int j = 0; j < 3; ++j) {
            int n = (wnt0 + j) * 16 + (lane & 15);
            float bb = b2v[n];
            #pragma unroll
            for (int r = 0; r < 4; ++r) {
                long tok = tok0 + wm * 16 + 4 * (lane >> 4) + r;
                X[tok * CC + n] += acc2[j][r] + bb;
            }
        }
    }
}

// ---------------- fallback fp32 MLP (only if ws too small) ----------------
#define MT 8
__global__ __launch_bounds__(128) void k_mlp(const float* __restrict__ Y, float* __restrict__ X,
                                             const float* __restrict__ w1, const float* __restrict__ b1v,
                                             const float* __restrict__ w2, const float* __restrict__ b2v) {
    __shared__ float yt[MT * CC];
    __shared__ float hb[MT * 4 * CC];
    long tok0 = (long)blockIdx.x * MT;
    int tid = threadIdx.x;

    for (int idx = tid; idx < MT * CC; idx += 128)
        yt[idx] = Y[tok0 * CC + idx];
    __syncthreads();

    for (int o = tid; o < 4 * CC; o += 128) {
        const float* wrow = w1 + (long)o * CC;
        float acc[MT];
        float bb = b1v[o];
        #pragma unroll
        for (int t = 0; t < MT; ++t) acc[t] = bb;
        for (int c = 0; c < CC; ++c) {
            float w = wrow[c];
            #pragma unroll
            for (int t = 0; t < MT; ++t) acc[t] += yt[t * CC + c] * w;
        }
        #pragma unroll
        for (int t = 0; t < MT; ++t) {
            float s = acc[t];
            float u = tanhf(0.7978845608028654f * (s + 0.044715f * s * s * s));
            hb[t * (4 * CC) + o] = 0.5f * s * (1.f + u);
        }
    }
    __syncthreads();

    if (tid < CC) {
        const float* wrow = w2 + (long)tid * (4 * CC);
        float acc[MT];
        float bb = b2v[tid];
        #pragma unroll
        for (int t = 0; t < MT; ++t) acc[t] = bb;
        for (int c = 0; c < 4 * CC; ++c) {
            float w = wrow[c];
            #pragma unroll
            for (int t = 0; t < MT; ++t) acc[t] += hb[t * (4 * CC) + c] * w;
        }
        #pragma unroll
        for (int t = 0; t < MT; ++t)
            X[(tok0 + t) * CC + tid] += acc[t];
    }
}

// ---------------- crop + NHWC->NCHW ----------------
__global__ void k_crop(const float* __restrict__ X, float* __restrict__ out) {
    long id = (long)blockIdx.x * 256 + threadIdx.x;
    const long total = (long)BB * CC * LAT_ * LON_;
    if (id >= total) return;
    int w = (int)(id % LON_);
    long t = id / LON_;
    int lat = (int)(t % LAT_); t /= LAT_;
    int c = (int)(t % CC);
    int b = (int)(t / CC);
    out[id] = X[(((long)b * HH + (lat + PT_)) * WWID + w) * CC + c];
}

extern "C" void kernel_launch(void* const* d_in, const int* in_sizes, int n_in,
                              void* d_out, int out_size, void* d_ws, size_t ws_size,
                              hipStream_t stream) {
    const float* x     = (const float*)d_in[0];
    const float* g1    = (const float*)d_in[1];
    const float* b1    = (const float*)d_in[2];
    const float* qkvw  = (const float*)d_in[3];
    const float* qkvb  = (const float*)d_in[4];
    const float* projw = (const float*)d_in[5];
    const float* projb = (const float*)d_in[6];
    const float* rpb   = (const float*)d_in[7];
    const float* g2    = (const float*)d_in[8];
    const float* b2    = (const float*)d_in[9];
    const float* f1w   = (const float*)d_in[10];
    const float* f1b   = (const float*)d_in[11];
    const float* f2w   = (const float*)d_in[12];
    const float* f2b   = (const float*)d_in[13];

    float* X = (float*)d_ws;
    float* Y = X + (long)BB * HH * WWID * CC;
    unsigned short* wbf = (unsigned short*)(Y + (long)BB * HH * WWID * CC);
    const size_t WS_NEEDED = (size_t)BB * HH * WWID * CC * 4 * 2 + 147456 * 2;
    const bool use_mfma = ws_size >= WS_NEEDED;

    const long padtot = (long)BB * HH * WWID * CC;
    const int ntok = BB * HH * WWID;

    k_pad<<<(int)((padtot + 255) / 256), 256, 0, stream>>>(x, X);
    if (use_mfma)
        k_wprep<<<576, 256, 0, stream>>>(f1w, f2w, wbf);

    for (int i = 0; i < 2; ++i) {
        k_ln<<<ntok / 4, 256, 0, stream>>>(X, Y, g1 + i * CC, b1 + i * CC);
        if (i == 0) {
            k_attn<0><<<BB * NWIN, ATHREADS, 0, stream>>>(Y, X,
                qkvw + (long)i * 3 * CC * CC, qkvb + (long)i * 3 * CC,
                projw + (long)i * CC * CC, projb + (long)i * CC,
                rpb + (long)i * 253 * NHD);
        } else {
            k_attn<1><<<BB * NWIN, ATHREADS, 0, stream>>>(Y, X,
                qkvw + (long)i * 3 * CC * CC, qkvb + (long)i * 3 * CC,
                projw + (long)i * CC * CC, projb + (long)i * CC,
                rpb + (long)i * 253 * NHD);
        }
        if (use_mfma) {
            k_mlp_mfma<<<ntok / 32, 256, 0, stream>>>(X,
                g2 + i * CC, b2 + i * CC,
                wbf + (long)i * 36864, f1b + (long)i * 4 * CC,
                wbf + 73728 + (long)i * 36864, f2b + (long)i * CC);
        } else {
            k_ln<<<ntok / 4, 256, 0, stream>>>(X, Y, g2 + i * CC, b2 + i * CC);
            k_mlp<<<ntok / MT, 128, 0, stream>>>(Y, X,
                f1w + (long)i * 4 * CC * CC, f1b + (long)i * 4 * CC,
                f2w + (long)i * CC * 4 * CC, f2b + (long)i * CC);
        }
    }

    const long croptot = (long)BB * CC * LAT_ * LON_;
    k_crop<<<(int)((croptot + 255) / 256), 256, 0, stream>>>(X, (float*)d_out);
}

// Round 5
// 649.088 us; speedup vs baseline: 11.0918x; 2.3492x over previous
//
#include <hip/hip_runtime.h>
#include <math.h>

// ---- problem constants ----
#define BB    2
#define CC    96
#define NHD   4
#define HDIM  24
#define LAT_  181
#define LON_  360
#define PT_   2
#define HH    186
#define WWID  360
#define WH_   6
#define WW_   12
#define NTOK  72
#define SH_   3
#define SW_   6
#define NWH_  31
#define NWW_  30
#define NWIN  930
#define SCALE_ 0.20412414523193154f   // 24^-0.5

typedef __attribute__((ext_vector_type(8))) short short8v;
typedef __attribute__((ext_vector_type(4))) float f32x4;

__device__ __forceinline__ unsigned short pk_bf16(float x) {
    unsigned u = __float_as_uint(x);
    unsigned r = (u + 0x7fffu + ((u >> 16) & 1u)) >> 16;   // RNE
    return (unsigned short)r;
}
__device__ __forceinline__ uint2 pk4(float a, float b, float c, float d) {
    uint2 r;
    r.x = (unsigned)pk_bf16(a) | ((unsigned)pk_bf16(b) << 16);
    r.y = (unsigned)pk_bf16(c) | ((unsigned)pk_bf16(d) << 16);
    return r;
}

// ---------------- pad + NCHW->NHWC ----------------
__global__ void k_pad(const float* __restrict__ in, float* __restrict__ X) {
    long id = (long)blockIdx.x * 256 + threadIdx.x;
    const long total = (long)BB * HH * WWID * CC;
    if (id >= total) return;
    int c = (int)(id % CC);
    long t = id / CC;
    int w = (int)(t % WWID); t /= WWID;
    int h = (int)(t % HH);
    int b = (int)(t / HH);
    int lat = h - PT_;
    float v = 0.f;
    if (lat >= 0 && lat < LAT_)
        v = in[(((long)b * CC + c) * LAT_ + lat) * LON_ + w];
    X[id] = v;
}

__device__ __forceinline__ int regionOf(int hr, int wr) {
    int rh = hr < (HH - WH_) ? 0 : (hr < (HH - SH_) ? 1 : 2);
    int rw = wr < (WWID - WW_) ? 0 : (wr < (WWID - SW_) ? 1 : 2);
    return rh * 3 + rw;
}

// ---------------- weight prep ----------------
// layout (shorts): [0)        w1f  2 x 36864   (MLP fc1 frag-ordered)
//                  [73728)    w2f  2 x 36864   (MLP fc2 frag-ordered)
//                  [147456)   qkvw_bf 2 x 288*96 (row-major)
//                  [202752)   projw_bf 2 x 96*96 (row-major)
__global__ void k_wprep(const float* __restrict__ f1w, const float* __restrict__ f2w,
                        const float* __restrict__ qkvw, const float* __restrict__ projw,
                        unsigned short* __restrict__ wbf) {
    int id = blockIdx.x * 256 + threadIdx.x;   // 221184 total
    if (id < 73728) {
        int layer = id / 36864, rem = id % 36864;
        int ks = rem / 12288, r2 = rem % 12288;
        int nt = r2 / 512, r3 = r2 % 512;
        int lane = r3 / 8, e = r3 % 8;
        int o = nt * 16 + (lane & 15);
        int c = ks * 32 + 8 * (lane >> 4) + e;
        wbf[(long)layer * 36864 + rem] = pk_bf16(f1w[((long)layer * 384 + o) * 96 + c]);
    } else if (id < 147456) {
        int id2 = id - 73728;
        int layer = id2 / 36864, rem = id2 % 36864;
        int ks = rem / 3072, r2 = rem % 3072;
        int nt = r2 / 512, r3 = r2 % 512;
        int lane = r3 / 8, e = r3 % 8;
        int o = nt * 16 + (lane & 15);
        int c = ks * 32 + 8 * (lane >> 4) + e;
        wbf[73728 + (long)layer * 36864 + rem] = pk_bf16(f2w[((long)layer * 96 + o) * 384 + c]);
    } else if (id < 202752) {
        int rem = id - 147456;          // plain row-major cast
        wbf[id] = pk_bf16(qkvw[rem]);
    } else if (id < 221184) {
        int rem = id - 202752;
        wbf[id] = pk_bf16(projw[rem]);
    }
}

// ---------------- fused LN1 + MFMA window attention + proj + residual ----------------
// LDS (129312 B):
//   [0)       As [80][104] bf16 (LN'd window)  | ps [4][80][104] bf16 (probs, alias)
//   [66560)   qs [4][80][24] bf16              | os [80][104] bf16 (alias)
//   [83200)   ks [4][80][24] bf16
//   [98560)   vt [4][32][104] bf16  (V transposed: [h][d][token])
//   [125184)  rpb_s f32 [253*4]
//   [129232)  regj u8 [80]
template <int SHIFT>
__global__ __launch_bounds__(512, 2) void k_attn(float* __restrict__ X,
        const float* __restrict__ gg, const float* __restrict__ bb,
        const unsigned short* __restrict__ wqkv, const float* __restrict__ qkvb,
        const unsigned short* __restrict__ wprj, const float* __restrict__ projb,
        const float* __restrict__ rpb) {
    __shared__ __align__(16) unsigned char smem[129312];
    unsigned short* As  = (unsigned short*)smem;
    unsigned short* ps  = (unsigned short*)smem;
    unsigned short* qs  = (unsigned short*)(smem + 66560);
    unsigned short* os  = (unsigned short*)(smem + 66560);
    unsigned short* ks  = (unsigned short*)(smem + 83200);
    unsigned short* vt  = (unsigned short*)(smem + 98560);
    float* rpb_s        = (float*)(smem + 125184);
    unsigned char* regj = smem + 129232;

    int bid = blockIdx.x;
    int b = bid / NWIN, wi = bid % NWIN;
    int nwh = wi / NWW_, nww = wi % NWW_;
    int tid = threadIdx.x;
    int wv = tid >> 6, lane = tid & 63;
    int li = lane & 15, gq = lane >> 4;

    // zero-init pad regions read by MFMA (NaN containment):
    //  - vt entirely (d rows 24..31 + token cols 80..95 stay zero)
    //  - As rows 72..79
    {
        unsigned* vz = (unsigned*)vt;
        for (int idx = tid; idx < 6656; idx += 512) vz[idx] = 0u;
        unsigned* az = (unsigned*)(As + 72 * 104);
        for (int idx = tid; idx < 416; idx += 512) az[idx] = 0u;
    }
    for (int idx = tid; idx < 1012; idx += 512) rpb_s[idx] = rpb[idx];
    if (tid < 80) {
        int t = tid < 72 ? tid : 71;
        int th = t / 12, tw = t % 12;
        regj[tid] = (unsigned char)(SHIFT ? regionOf(nwh * WH_ + th, nww * WW_ + tw) : 0);
    }

    // ---- phase 0: gather window + LN1 -> As (bf16) ----
    {
        int sub = lane >> 3, p = lane & 7;
        #pragma unroll
        for (int tt = 0; tt < 2; ++tt) {
            if (tt == 0 || sub == 0) {
                int t = wv * 9 + tt * 8 + sub;       // 0..71
                int th = t / 12, tw = t % 12;
                int hr = nwh * WH_ + th, wr = nww * WW_ + tw;
                int ho = SHIFT ? (hr + SH_) % HH : hr;
                int wo = SHIFT ? (wr + SW_) % WWID : wr;
                const float* xr = X + (((long)b * HH + ho) * WWID + wo) * CC;
                float4 a  = *(const float4*)(xr + p * 4);
                float4 c4 = *(const float4*)(xr + p * 4 + 32);
                float4 e4 = *(const float4*)(xr + p * 4 + 64);
                float s  = a.x + a.y + a.z + a.w + c4.x + c4.y + c4.z + c4.w + e4.x + e4.y + e4.z + e4.w;
                float sq = a.x*a.x + a.y*a.y + a.z*a.z + a.w*a.w + c4.x*c4.x + c4.y*c4.y + c4.z*c4.z + c4.w*c4.w
                         + e4.x*e4.x + e4.y*e4.y + e4.z*e4.z + e4.w*e4.w;
                #pragma unroll
                for (int off = 1; off < 8; off <<= 1) {
                    s  += __shfl_xor(s, off);
                    sq += __shfl_xor(sq, off);
                }
                float mean = s * (1.f / CC);
                float var = sq * (1.f / CC) - mean * mean;
                float rs = rsqrtf(var + 1e-5f);
                float4 g0 = *(const float4*)(gg + p * 4);
                float4 g1v = *(const float4*)(gg + p * 4 + 32);
                float4 g2v = *(const float4*)(gg + p * 4 + 64);
                float4 t0 = *(const float4*)(bb + p * 4);
                float4 t1 = *(const float4*)(bb + p * 4 + 32);
                float4 t2 = *(const float4*)(bb + p * 4 + 64);
                *(uint2*)(As + t * 104 + p * 4) =
                    pk4((a.x - mean) * rs * g0.x + t0.x, (a.y - mean) * rs * g0.y + t0.y,
                        (a.z - mean) * rs * g0.z + t0.z, (a.w - mean) * rs * g0.w + t0.w);
                *(uint2*)(As + t * 104 + p * 4 + 32) =
                    pk4((c4.x - mean) * rs * g1v.x + t1.x, (c4.y - mean) * rs * g1v.y + t1.y,
                        (c4.z - mean) * rs * g1v.z + t1.z, (c4.w - mean) * rs * g1v.w + t1.w);
                *(uint2*)(As + t * 104 + p * 4 + 64) =
                    pk4((e4.x - mean) * rs * g2v.x + t2.x, (e4.y - mean) * rs * g2v.y + t2.y,
                        (e4.z - mean) * rs * g2v.z + t2.z, (e4.w - mean) * rs * g2v.w + t2.w);
            }
        }
    }
    __syncthreads();

    // ---- QKV: C[o][token] = Wqkv @ Y^T, per o-tile row ----
    for (int mt = wv; mt < 18; mt += 8) {
        short8v aw[3];
        #pragma unroll
        for (int ksi = 0; ksi < 3; ++ksi)
            aw[ksi] = *(const short8v*)(wqkv + (mt * 16 + li) * 96 + ksi * 32 + 8 * gq);
        float bias4[4];
        #pragma unroll
        for (int r = 0; r < 4; ++r) bias4[r] = qkvb[mt * 16 + 4 * gq + r];
        f32x4 acc[5];
        #pragma unroll
        for (int nt = 0; nt < 5; ++nt) acc[nt] = (f32x4){0.f, 0.f, 0.f, 0.f};
        #pragma unroll
        for (int nt = 0; nt < 5; ++nt)
            #pragma unroll
            for (int ksi = 0; ksi < 3; ++ksi) {
                short8v by = *(const short8v*)(As + (nt * 16 + li) * 104 + ksi * 32 + 8 * gq);
                acc[nt] = __builtin_amdgcn_mfma_f32_16x16x32_bf16(aw[ksi], by, acc[nt], 0, 0, 0);
            }
        int which = mt / 6, mtl = mt % 6;
        int oo0 = mtl * 16 + 4 * gq;
        int h = oo0 / 24, d0 = oo0 % 24;       // 4-aligned block never crosses head (24%4==0)
        #pragma unroll
        for (int nt = 0; nt < 5; ++nt) {
            int token = nt * 16 + li;
            if (which == 2) {
                #pragma unroll
                for (int r = 0; r < 4; ++r)
                    vt[(h * 32 + d0 + r) * 104 + token] = pk_bf16(acc[nt][r] + bias4[r]);
            } else {
                float v0 = acc[nt][0] + bias4[0], v1 = acc[nt][1] + bias4[1];
                float v2 = acc[nt][2] + bias4[2], v3 = acc[nt][3] + bias4[3];
                if (which == 0) { v0 *= SCALE_; v1 *= SCALE_; v2 *= SCALE_; v3 *= SCALE_; }
                unsigned short* dst = (which == 0 ? qs : ks) + (h * 80 + token) * 24 + d0;
                *(uint2*)dst = pk4(v0, v1, v2, v3);
            }
        }
    }
    __syncthreads();

    // ---- S^T = K @ Q^T per (head, i-tile) strip + softmax -> ps[i][j] ----
    for (int u = wv; u < 20; u += 8) {
        int h = u / 5, nt = u % 5;
        int i = nt * 16 + li;
        // zero P pad j in [80,96)
        *(uint2*)(ps + (h * 80 + i) * 104 + 80 + 4 * gq) = (uint2){0u, 0u};
        short8v bq = {0,0,0,0,0,0,0,0};
        if (gq < 3) bq = *(const short8v*)(qs + (h * 80 + i) * 24 + 8 * gq);
        int thi = i / 12, twi = i % 12;
        int regi = regj[i];
        float p[20];
        float sum = 0.f;
        #pragma unroll
        for (int mt = 0; mt < 5; ++mt) {
            short8v ak = {0,0,0,0,0,0,0,0};
            if (gq < 3) ak = *(const short8v*)(ks + (h * 80 + mt * 16 + li) * 24 + 8 * gq);
            f32x4 ct = __builtin_amdgcn_mfma_f32_16x16x32_bf16(ak, bq, (f32x4){0.f,0.f,0.f,0.f}, 0, 0, 0);
            #pragma unroll
            for (int r = 0; r < 4; ++r) {
                int j = mt * 16 + 4 * gq + r;
                int thj = j / 12, twj = j % 12;
                int ridx = (thi - thj + WH_ - 1) * (2 * WW_ - 1) + (twi - twj + WW_ - 1);
                ridx = min(max(ridx, 0), 252);
                float sv = ct[r] + rpb_s[ridx * 4 + h];
                if (SHIFT) { if ((int)regj[j] != regi) sv -= 100.f; }
                float pv = (j < 72) ? __expf(sv) : 0.f;
                p[mt * 4 + r] = pv;
                sum += pv;
            }
        }
        sum += __shfl_xor(sum, 16);
        sum += __shfl_xor(sum, 32);
        float inv = 1.f / sum;
        #pragma unroll
        for (int mt = 0; mt < 5; ++mt)
            *(uint2*)(ps + (h * 80 + i) * 104 + mt * 16 + 4 * gq) =
                pk4(p[mt*4+0] * inv, p[mt*4+1] * inv, p[mt*4+2] * inv, p[mt*4+3] * inv);
    }
    __syncthreads();

    // ---- PV: O[i][d] = P @ V  -> os[i][h*24+d] ----
    for (int u = wv; u < 40; u += 8) {
        int h = u / 10, rm = u % 10, mt = rm >> 1, nt2 = rm & 1;
        f32x4 acc = (f32x4){0.f, 0.f, 0.f, 0.f};
        #pragma unroll
        for (int ksi = 0; ksi < 3; ++ksi) {
            short8v ap = *(const short8v*)(ps + (h * 80 + mt * 16 + li) * 104 + ksi * 32 + 8 * gq);
            short8v bv = *(const short8v*)(vt + (h * 32 + nt2 * 16 + li) * 104 + ksi * 32 + 8 * gq);
            acc = __builtin_amdgcn_mfma_f32_16x16x32_bf16(ap, bv, acc, 0, 0, 0);
        }
        int d = nt2 * 16 + li;
        if (d < 24) {
            #pragma unroll
            for (int r = 0; r < 4; ++r)
                os[(mt * 16 + 4 * gq + r) * 104 + h * 24 + d] = pk_bf16(acc[r]);
        }
    }
    __syncthreads();

    // ---- proj + residual scatter: X[token][o] += O @ Wp^T + b ----
    for (int u = wv; u < 30; u += 8) {
        int mt = u / 6, nt = u % 6;
        f32x4 acc = (f32x4){0.f, 0.f, 0.f, 0.f};
        #pragma unroll
        for (int ksi = 0; ksi < 3; ++ksi) {
            short8v ao = *(const short8v*)(os + (mt * 16 + li) * 104 + ksi * 32 + 8 * gq);
            short8v bw = *(const short8v*)(wprj + (nt * 16 + li) * 96 + ksi * 32 + 8 * gq);
            acc = __builtin_amdgcn_mfma_f32_16x16x32_bf16(ao, bw, acc, 0, 0, 0);
        }
        int o = nt * 16 + li;
        float bo = projb[o];
        #pragma unroll
        for (int r = 0; r < 4; ++r) {
            int token = mt * 16 + 4 * gq + r;
            if (token < 72) {
                int th = token / 12, tw = token % 12;
                int hr = nwh * WH_ + th, wr = nww * WW_ + tw;
                int ho = SHIFT ? (hr + SH_) % HH : hr;
                int wo = SHIFT ? (wr + SW_) % WWID : wr;
                X[(((long)b * HH + ho) * WWID + wo) * CC + o] += acc[r] + bo;
            }
        }
    }
}

// ---------------- fused LN2 + MFMA MLP (unchanged, validated) ----------------
__global__ __launch_bounds__(256, 4) void k_mlp_mfma(float* __restrict__ X,
        const float* __restrict__ g, const float* __restrict__ bta,
        const unsigned short* __restrict__ w1f, const float* __restrict__ b1v,
        const unsigned short* __restrict__ w2f, const float* __restrict__ b2v) {
    __shared__ __align__(16) unsigned short As[32 * 120];
    __shared__ __align__(16) unsigned short Hs[32 * 392];
    long tok0 = (long)blockIdx.x * 32;
    int tid = threadIdx.x;

    {
        int t = tid >> 3, p = tid & 7;
        const float* xr = X + (tok0 + t) * CC;
        float4 a = *(const float4*)(xr + p * 4);
        float4 b = *(const float4*)(xr + p * 4 + 32);
        float4 c4 = *(const float4*)(xr + p * 4 + 64);
        float s  = a.x + a.y + a.z + a.w + b.x + b.y + b.z + b.w + c4.x + c4.y + c4.z + c4.w;
        float sq = a.x*a.x + a.y*a.y + a.z*a.z + a.w*a.w + b.x*b.x + b.y*b.y + b.z*b.z + b.w*b.w
                 + c4.x*c4.x + c4.y*c4.y + c4.z*c4.z + c4.w*c4.w;
        #pragma unroll
        for (int off = 1; off < 8; off <<= 1) {
            s  += __shfl_xor(s, off);
            sq += __shfl_xor(sq, off);
        }
        float mean = s * (1.f / CC);
        float var = sq * (1.f / CC) - mean * mean;
        float rs = rsqrtf(var + 1e-5f);
        float4 g0 = *(const float4*)(g + p * 4);
        float4 g1 = *(const float4*)(g + p * 4 + 32);
        float4 g2 = *(const float4*)(g + p * 4 + 64);
        float4 t0 = *(const float4*)(bta + p * 4);
        float4 t1 = *(const float4*)(bta + p * 4 + 32);
        float4 t2 = *(const float4*)(bta + p * 4 + 64);
        unsigned short* arow = As + t * 120;
        arow[p*4+0]  = pk_bf16((a.x - mean) * rs * g0.x + t0.x);
        arow[p*4+1]  = pk_bf16((a.y - mean) * rs * g0.y + t0.y);
        arow[p*4+2]  = pk_bf16((a.z - mean) * rs * g0.z + t0.z);
        arow[p*4+3]  = pk_bf16((a.w - mean) * rs * g0.w + t0.w);
        arow[p*4+32] = pk_bf16((b.x - mean) * rs * g1.x + t1.x);
        arow[p*4+33] = pk_bf16((b.y - mean) * rs * g1.y + t1.y);
        arow[p*4+34] = pk_bf16((b.z - mean) * rs * g1.z + t1.z);
        arow[p*4+35] = pk_bf16((b.w - mean) * rs * g1.w + t1.w);
        arow[p*4+64] = pk_bf16((c4.x - mean) * rs * g2.x + t2.x);
        arow[p*4+65] = pk_bf16((c4.y - mean) * rs * g2.y + t2.y);
        arow[p*4+66] = pk_bf16((c4.z - mean) * rs * g2.z + t2.z);
        arow[p*4+67] = pk_bf16((c4.w - mean) * rs * g2.w + t2.w);
    }
    __syncthreads();

    int w = tid >> 6, lane = tid & 63;
    int wm = w & 1;
    int row = wm * 16 + (lane & 15);
    int kbase = 8 * (lane >> 4);

    {
        int wnh = w >> 1;
        short8v afr[3];
        #pragma unroll
        for (int ks = 0; ks < 3; ++ks)
            afr[ks] = *(const short8v*)(As + row * 120 + ks * 32 + kbase);
        f32x4 acc[12];
        #pragma unroll
        for (int j = 0; j < 12; ++j) acc[j] = (f32x4){0.f, 0.f, 0.f, 0.f};
        const short8v* wb = (const short8v*)w1f;
        #pragma unroll
        for (int j = 0; j < 12; ++j) {
            int nt = wnh * 12 + j;
            #pragma unroll
            for (int ks = 0; ks < 3; ++ks) {
                short8v bfr = wb[(ks * 24 + nt) * 64 + lane];
                acc[j] = __builtin_amdgcn_mfma_f32_16x16x32_bf16(afr[ks], bfr, acc[j], 0, 0, 0);
            }
        }
        #pragma unroll
        for (int j = 0; j < 12; ++j) {
            int n = (wnh * 12 + j) * 16 + (lane & 15);
            float bb = b1v[n];
            #pragma unroll
            for (int r = 0; r < 4; ++r) {
                float s = acc[j][r] + bb;
                float z = s + 0.044715f * s * s * s;
                float gl = s / (1.f + __expf(-1.5957691216057308f * z));
                Hs[(wm * 16 + 4 * (lane >> 4) + r) * 392 + n] = pk_bf16(gl);
            }
        }
    }
    __syncthreads();

    {
        int wnt0 = (w >> 1) * 3;
        f32x4 acc2[3];
        #pragma unroll
        for (int j = 0; j < 3; ++j) acc2[j] = (f32x4){0.f, 0.f, 0.f, 0.f};
        const short8v* wb2 = (const short8v*)w2f;
        #pragma unroll
        for (int ks = 0; ks < 12; ++ks) {
            short8v a2 = *(const short8v*)(Hs + row * 392 + ks * 32 + kbase);
            #pragma unroll
            for (int j = 0; j < 3; ++j) {
                short8v bfr = wb2[(ks * 6 + wnt0 + j) * 64 + lane];
                acc2[j] = __builtin_amdgcn_mfma_f32_16x16x32_bf16(a2, bfr, acc2[j], 0, 0, 0);
            }
        }
        #pragma unroll
        for (int j = 0; j < 3; ++j) {
            int n = (wnt0 + j) * 16 + (lane & 15);
            float bb = b2v[n];
            #pragma unroll
            for (int r = 0; r < 4; ++r) {
                long tok = tok0 + wm * 16 + 4 * (lane >> 4) + r;
                X[tok * CC + n] += acc2[j][r] + bb;
            }
        }
    }
}

// ---------------- crop + NHWC->NCHW ----------------
__global__ void k_crop(const float* __restrict__ X, float* __restrict__ out) {
    long id = (long)blockIdx.x * 256 + threadIdx.x;
    const long total = (long)BB * CC * LAT_ * LON_;
    if (id >= total) return;
    int w = (int)(id % LON_);
    long t = id / LON_;
    int lat = (int)(t % LAT_); t /= LAT_;
    int c = (int)(t % CC);
    int b = (int)(t / CC);
    out[id] = X[(((long)b * HH + (lat + PT_)) * WWID + w) * CC + c];
}

extern "C" void kernel_launch(void* const* d_in, const int* in_sizes, int n_in,
                              void* d_out, int out_size, void* d_ws, size_t ws_size,
                              hipStream_t stream) {
    const float* x     = (const float*)d_in[0];
    const float* g1    = (const float*)d_in[1];
    const float* b1    = (const float*)d_in[2];
    const float* qkvw  = (const float*)d_in[3];
    const float* qkvb  = (const float*)d_in[4];
    const float* projw = (const float*)d_in[5];
    const float* projb = (const float*)d_in[6];
    const float* rpb   = (const float*)d_in[7];
    const float* g2    = (const float*)d_in[8];
    const float* b2    = (const float*)d_in[9];
    const float* f1w   = (const float*)d_in[10];
    const float* f1b   = (const float*)d_in[11];
    const float* f2w   = (const float*)d_in[12];
    const float* f2b   = (const float*)d_in[13];

    float* X = (float*)d_ws;                                  // 51.4 MB
    unsigned short* wbf = (unsigned short*)(X + (long)BB * HH * WWID * CC);

    const long padtot = (long)BB * HH * WWID * CC;
    const int ntok = BB * HH * WWID;

    k_pad<<<(int)((padtot + 255) / 256), 256, 0, stream>>>(x, X);
    k_wprep<<<864, 256, 0, stream>>>(f1w, f2w, qkvw, projw, wbf);

    for (int i = 0; i < 2; ++i) {
        const unsigned short* wqkv_bf = wbf + 147456 + (long)i * 27648;
        const unsigned short* wprj_bf = wbf + 202752 + (long)i * 9216;
        if (i == 0) {
            k_attn<0><<<BB * NWIN, 512, 0, stream>>>(X, g1, b1,
                wqkv_bf, qkvb, wprj_bf, projb, rpb);
        } else {
            k_attn<1><<<BB * NWIN, 512, 0, stream>>>(X, g1 + CC, b1 + CC,
                wqkv_bf, qkvb + 3 * CC, wprj_bf, projb + CC, rpb + 253 * NHD);
        }
        k_mlp_mfma<<<ntok / 32, 256, 0, stream>>>(X,
            g2 + i * CC, b2 + i * CC,
            wbf + (long)i * 36864, f1b + i * 4 * CC,
            wbf + 73728 + (long)i * 36864, f2b + i * CC);
    }

    const long croptot = (long)BB * CC * LAT_ * LON_;
    k_crop<<<(int)((croptot + 255) / 256), 256, 0, stream>>>(X, (float*)d_out);
}

// Round 6
// 412.375 us; speedup vs baseline: 17.4588x; 1.5740x over previous
//
#include <hip/hip_runtime.h>
#include <math.h>

// ---- problem constants ----
#define BB    2
#define CC    96
#define NHD   4
#define HDIM  24
#define LAT_  181
#define LON_  360
#define PT_   2
#define HH    186
#define WWID  360
#define WH_   6
#define WW_   12
#define NTOK  72
#define SH_   3
#define SW_   6
#define NWH_  31
#define NWW_  30
#define NWIN  930
#define SCALE_ 0.20412414523193154f   // 24^-0.5

typedef __attribute__((ext_vector_type(8))) short short8v;
typedef __attribute__((ext_vector_type(4))) float f32x4;

__device__ __forceinline__ unsigned short pk_bf16(float x) {
    unsigned u = __float_as_uint(x);
    unsigned r = (u + 0x7fffu + ((u >> 16) & 1u)) >> 16;   // RNE
    return (unsigned short)r;
}
__device__ __forceinline__ uint2 pk4(float a, float b, float c, float d) {
    uint2 r;
    r.x = (unsigned)pk_bf16(a) | ((unsigned)pk_bf16(b) << 16);
    r.y = (unsigned)pk_bf16(c) | ((unsigned)pk_bf16(d) << 16);
    return r;
}

// ---------------- pad + NCHW->NHWC via LDS tile transpose ----------------
// grid: b(2) x h(186) x wt(12) x ct(3); block 256 = 32x8; tile[32][33]
__global__ __launch_bounds__(256) void k_pad2(const float* __restrict__ in, float* __restrict__ X) {
    int bid = blockIdx.x;
    int ct = bid % 3; bid /= 3;
    int wt = bid % 12; bid /= 12;
    int h = bid % HH; int b = bid / HH;
    int lat = h - PT_;
    int tx = threadIdx.x & 31, ty = threadIdx.x >> 5;
    __shared__ float tile[32][33];
    if (lat >= 0 && lat < LAT_) {
        int w = wt * 32 + tx;
        #pragma unroll
        for (int i = 0; i < 4; ++i) {
            int c = ct * 32 + ty + 8 * i;
            float v = 0.f;
            if (w < WWID) v = in[((long)(b * CC + c)) * (LAT_ * LON_) + lat * LON_ + w];
            tile[ty + 8 * i][tx] = v;
        }
    } else {
        #pragma unroll
        for (int i = 0; i < 4; ++i) tile[ty + 8 * i][tx] = 0.f;
    }
    __syncthreads();
    #pragma unroll
    for (int i = 0; i < 4; ++i) {
        int w = wt * 32 + ty + 8 * i;
        if (w < WWID)
            X[(((long)(b * HH + h)) * WWID + w) * CC + ct * 32 + tx] = tile[tx][ty + 8 * i];
    }
}

// ---------------- crop + NHWC->NCHW via LDS tile transpose ----------------
// grid: b(2) x lat(181) x wt(12) x ct(3)
__global__ __launch_bounds__(256) void k_crop2(const float* __restrict__ X, float* __restrict__ out) {
    int bid = blockIdx.x;
    int ct = bid % 3; bid /= 3;
    int wt = bid % 12; bid /= 12;
    int lat = bid % LAT_; int b = bid / LAT_;
    int h = lat + PT_;
    int tx = threadIdx.x & 31, ty = threadIdx.x >> 5;
    __shared__ float tile[32][33];
    #pragma unroll
    for (int i = 0; i < 4; ++i) {
        int w = wt * 32 + ty + 8 * i;
        if (w < WWID)
            tile[ty + 8 * i][tx] = X[(((long)(b * HH + h)) * WWID + w) * CC + ct * 32 + tx];
    }
    __syncthreads();
    {
        int w = wt * 32 + tx;
        if (w < WWID) {
            #pragma unroll
            for (int i = 0; i < 4; ++i) {
                int c = ct * 32 + ty + 8 * i;
                out[((long)(b * CC + c)) * (LAT_ * LON_) + lat * LON_ + w] = tile[tx][ty + 8 * i];
            }
        }
    }
}

__device__ __forceinline__ int regionOf(int hr, int wr) {
    int rh = hr < (HH - WH_) ? 0 : (hr < (HH - SH_) ? 1 : 2);
    int rw = wr < (WWID - WW_) ? 0 : (wr < (WWID - SW_) ? 1 : 2);
    return rh * 3 + rw;
}

// ---------------- weight prep ----------------
// layout (shorts): [0)        w1f  2 x 36864   (MLP fc1 frag-ordered)
//                  [73728)    w2f  2 x 36864   (MLP fc2 frag-ordered)
//                  [147456)   qkvw_bf 2 x 288*96 (row-major)
//                  [202752)   projw_bf 2 x 96*96 (row-major)
__global__ void k_wprep(const float* __restrict__ f1w, const float* __restrict__ f2w,
                        const float* __restrict__ qkvw, const float* __restrict__ projw,
                        unsigned short* __restrict__ wbf) {
    int id = blockIdx.x * 256 + threadIdx.x;   // 221184 total
    if (id < 73728) {
        int layer = id / 36864, rem = id % 36864;
        int ks = rem / 12288, r2 = rem % 12288;
        int nt = r2 / 512, r3 = r2 % 512;
        int lane = r3 / 8, e = r3 % 8;
        int o = nt * 16 + (lane & 15);
        int c = ks * 32 + 8 * (lane >> 4) + e;
        wbf[(long)layer * 36864 + rem] = pk_bf16(f1w[((long)layer * 384 + o) * 96 + c]);
    } else if (id < 147456) {
        int id2 = id - 73728;
        int layer = id2 / 36864, rem = id2 % 36864;
        int ks = rem / 3072, r2 = rem % 3072;
        int nt = r2 / 512, r3 = r2 % 512;
        int lane = r3 / 8, e = r3 % 8;
        int o = nt * 16 + (lane & 15);
        int c = ks * 32 + 8 * (lane >> 4) + e;
        wbf[73728 + (long)layer * 36864 + rem] = pk_bf16(f2w[((long)layer * 96 + o) * 384 + c]);
    } else if (id < 202752) {
        int rem = id - 147456;          // plain row-major cast
        wbf[id] = pk_bf16(qkvw[rem]);
    } else if (id < 221184) {
        int rem = id - 202752;
        wbf[id] = pk_bf16(projw[rem]);
    }
}

// ---------------- fused LN1 + MFMA window attention + proj + residual ----------------
// LDS (129312 B):
//   [0)       As [80][104] bf16 (LN'd window)  | ps [4][80][104] bf16 (probs, alias)
//   [66560)   qs [4][80][24] bf16              | os [80][104] bf16 (alias)
//   [83200)   ks [4][80][24] bf16
//   [98560)   vt [4][32][104] bf16  (V transposed: [h][d][token])
//   [125184)  rpb_s f32 [253*4]
//   [129232)  regj u8 [80]
template <int SHIFT>
__global__ __launch_bounds__(512, 2) void k_attn(float* __restrict__ X,
        const float* __restrict__ gg, const float* __restrict__ bb,
        const unsigned short* __restrict__ wqkv, const float* __restrict__ qkvb,
        const unsigned short* __restrict__ wprj, const float* __restrict__ projb,
        const float* __restrict__ rpb) {
    __shared__ __align__(16) unsigned char smem[129312];
    unsigned short* As  = (unsigned short*)smem;
    unsigned short* ps  = (unsigned short*)smem;
    unsigned short* qs  = (unsigned short*)(smem + 66560);
    unsigned short* os  = (unsigned short*)(smem + 66560);
    unsigned short* ks  = (unsigned short*)(smem + 83200);
    unsigned short* vt  = (unsigned short*)(smem + 98560);
    float* rpb_s        = (float*)(smem + 125184);
    unsigned char* regj = smem + 129232;

    int bid = blockIdx.x;
    int b = bid / NWIN, wi = bid % NWIN;
    int nwh = wi / NWW_, nww = wi % NWW_;
    int tid = threadIdx.x;
    int wv = tid >> 6, lane = tid & 63;
    int li = lane & 15, gq = lane >> 4;

    // zero-init pad regions read by MFMA (NaN containment)
    {
        unsigned* vz = (unsigned*)vt;
        for (int idx = tid; idx < 6656; idx += 512) vz[idx] = 0u;
        unsigned* az = (unsigned*)(As + 72 * 104);
        for (int idx = tid; idx < 416; idx += 512) az[idx] = 0u;
    }
    for (int idx = tid; idx < 1012; idx += 512) rpb_s[idx] = rpb[idx];
    if (tid < 80) {
        int t = tid < 72 ? tid : 71;
        int th = t / 12, tw = t % 12;
        regj[tid] = (unsigned char)(SHIFT ? regionOf(nwh * WH_ + th, nww * WW_ + tw) : 0);
    }

    // ---- phase 0: gather window + LN1 -> As (bf16) ----
    {
        int sub = lane >> 3, p = lane & 7;
        #pragma unroll
        for (int tt = 0; tt < 2; ++tt) {
            if (tt == 0 || sub == 0) {
                int t = wv * 9 + tt * 8 + sub;       // 0..71
                int th = t / 12, tw = t % 12;
                int hr = nwh * WH_ + th, wr = nww * WW_ + tw;
                int ho = SHIFT ? (hr + SH_) % HH : hr;
                int wo = SHIFT ? (wr + SW_) % WWID : wr;
                const float* xr = X + (((long)b * HH + ho) * WWID + wo) * CC;
                float4 a  = *(const float4*)(xr + p * 4);
                float4 c4 = *(const float4*)(xr + p * 4 + 32);
                float4 e4 = *(const float4*)(xr + p * 4 + 64);
                float s  = a.x + a.y + a.z + a.w + c4.x + c4.y + c4.z + c4.w + e4.x + e4.y + e4.z + e4.w;
                float sq = a.x*a.x + a.y*a.y + a.z*a.z + a.w*a.w + c4.x*c4.x + c4.y*c4.y + c4.z*c4.z + c4.w*c4.w
                         + e4.x*e4.x + e4.y*e4.y + e4.z*e4.z + e4.w*e4.w;
                #pragma unroll
                for (int off = 1; off < 8; off <<= 1) {
                    s  += __shfl_xor(s, off);
                    sq += __shfl_xor(sq, off);
                }
                float mean = s * (1.f / CC);
                float var = sq * (1.f / CC) - mean * mean;
                float rs = rsqrtf(var + 1e-5f);
                float4 g0 = *(const float4*)(gg + p * 4);
                float4 g1v = *(const float4*)(gg + p * 4 + 32);
                float4 g2v = *(const float4*)(gg + p * 4 + 64);
                float4 t0 = *(const float4*)(bb + p * 4);
                float4 t1 = *(const float4*)(bb + p * 4 + 32);
                float4 t2 = *(const float4*)(bb + p * 4 + 64);
                *(uint2*)(As + t * 104 + p * 4) =
                    pk4((a.x - mean) * rs * g0.x + t0.x, (a.y - mean) * rs * g0.y + t0.y,
                        (a.z - mean) * rs * g0.z + t0.z, (a.w - mean) * rs * g0.w + t0.w);
                *(uint2*)(As + t * 104 + p * 4 + 32) =
                    pk4((c4.x - mean) * rs * g1v.x + t1.x, (c4.y - mean) * rs * g1v.y + t1.y,
                        (c4.z - mean) * rs * g1v.z + t1.z, (c4.w - mean) * rs * g1v.w + t1.w);
                *(uint2*)(As + t * 104 + p * 4 + 64) =
                    pk4((e4.x - mean) * rs * g2v.x + t2.x, (e4.y - mean) * rs * g2v.y + t2.y,
                        (e4.z - mean) * rs * g2v.z + t2.z, (e4.w - mean) * rs * g2v.w + t2.w);
            }
        }
    }
    __syncthreads();

    // ---- QKV: C[o][token] = Wqkv @ Y^T, per o-tile row ----
    for (int mt = wv; mt < 18; mt += 8) {
        short8v aw[3];
        #pragma unroll
        for (int ksi = 0; ksi < 3; ++ksi)
            aw[ksi] = *(const short8v*)(wqkv + (mt * 16 + li) * 96 + ksi * 32 + 8 * gq);
        float bias4[4];
        #pragma unroll
        for (int r = 0; r < 4; ++r) bias4[r] = qkvb[mt * 16 + 4 * gq + r];
        f32x4 acc[5];
        #pragma unroll
        for (int nt = 0; nt < 5; ++nt) acc[nt] = (f32x4){0.f, 0.f, 0.f, 0.f};
        #pragma unroll
        for (int nt = 0; nt < 5; ++nt)
            #pragma unroll
            for (int ksi = 0; ksi < 3; ++ksi) {
                short8v by = *(const short8v*)(As + (nt * 16 + li) * 104 + ksi * 32 + 8 * gq);
                acc[nt] = __builtin_amdgcn_mfma_f32_16x16x32_bf16(aw[ksi], by, acc[nt], 0, 0, 0);
            }
        int which = mt / 6, mtl = mt % 6;
        int oo0 = mtl * 16 + 4 * gq;
        int h = oo0 / 24, d0 = oo0 % 24;
        #pragma unroll
        for (int nt = 0; nt < 5; ++nt) {
            int token = nt * 16 + li;
            if (which == 2) {
                #pragma unroll
                for (int r = 0; r < 4; ++r)
                    vt[(h * 32 + d0 + r) * 104 + token] = pk_bf16(acc[nt][r] + bias4[r]);
            } else {
                float v0 = acc[nt][0] + bias4[0], v1 = acc[nt][1] + bias4[1];
                float v2 = acc[nt][2] + bias4[2], v3 = acc[nt][3] + bias4[3];
                if (which == 0) { v0 *= SCALE_; v1 *= SCALE_; v2 *= SCALE_; v3 *= SCALE_; }
                unsigned short* dst = (which == 0 ? qs : ks) + (h * 80 + token) * 24 + d0;
                *(uint2*)dst = pk4(v0, v1, v2, v3);
            }
        }
    }
    __syncthreads();

    // ---- S^T = K @ Q^T per (head, i-tile) strip + softmax -> ps[i][j] ----
    for (int u = wv; u < 20; u += 8) {
        int h = u / 5, nt = u % 5;
        int i = nt * 16 + li;
        *(uint2*)(ps + (h * 80 + i) * 104 + 80 + 4 * gq) = (uint2){0u, 0u};
        short8v bq = {0,0,0,0,0,0,0,0};
        if (gq < 3) bq = *(const short8v*)(qs + (h * 80 + i) * 24 + 8 * gq);
        int thi = i / 12, twi = i % 12;
        int regi = regj[i];
        float p[20];
        float sum = 0.f;
        #pragma unroll
        for (int mt = 0; mt < 5; ++mt) {
            short8v ak = {0,0,0,0,0,0,0,0};
            if (gq < 3) ak = *(const short8v*)(ks + (h * 80 + mt * 16 + li) * 24 + 8 * gq);
            f32x4 ct = __builtin_amdgcn_mfma_f32_16x16x32_bf16(ak, bq, (f32x4){0.f,0.f,0.f,0.f}, 0, 0, 0);
            #pragma unroll
            for (int r = 0; r < 4; ++r) {
                int j = mt * 16 + 4 * gq + r;
                int thj = j / 12, twj = j % 12;
                int ridx = (thi - thj + WH_ - 1) * (2 * WW_ - 1) + (twi - twj + WW_ - 1);
                ridx = min(max(ridx, 0), 252);
                float sv = ct[r] + rpb_s[ridx * 4 + h];
                if (SHIFT) { if ((int)regj[j] != regi) sv -= 100.f; }
                float pv = (j < 72) ? __expf(sv) : 0.f;
                p[mt * 4 + r] = pv;
                sum += pv;
            }
        }
        sum += __shfl_xor(sum, 16);
        sum += __shfl_xor(sum, 32);
        float inv = 1.f / sum;
        #pragma unroll
        for (int mt = 0; mt < 5; ++mt)
            *(uint2*)(ps + (h * 80 + i) * 104 + mt * 16 + 4 * gq) =
                pk4(p[mt*4+0] * inv, p[mt*4+1] * inv, p[mt*4+2] * inv, p[mt*4+3] * inv);
    }
    __syncthreads();

    // ---- PV: O[i][d] = P @ V  -> os[i][h*24+d] ----
    for (int u = wv; u < 40; u += 8) {
        int h = u / 10, rm = u % 10, mt = rm >> 1, nt2 = rm & 1;
        f32x4 acc = (f32x4){0.f, 0.f, 0.f, 0.f};
        #pragma unroll
        for (int ksi = 0; ksi < 3; ++ksi) {
            short8v ap = *(const short8v*)(ps + (h * 80 + mt * 16 + li) * 104 + ksi * 32 + 8 * gq);
            short8v bv = *(const short8v*)(vt + (h * 32 + nt2 * 16 + li) * 104 + ksi * 32 + 8 * gq);
            acc = __builtin_amdgcn_mfma_f32_16x16x32_bf16(ap, bv, acc, 0, 0, 0);
        }
        int d = nt2 * 16 + li;
        if (d < 24) {
            #pragma unroll
            for (int r = 0; r < 4; ++r)
                os[(mt * 16 + 4 * gq + r) * 104 + h * 24 + d] = pk_bf16(acc[r]);
        }
    }
    __syncthreads();

    // ---- proj + residual scatter: X[token][o] += O @ Wp^T + b ----
    for (int u = wv; u < 30; u += 8) {
        int mt = u / 6, nt = u % 6;
        f32x4 acc = (f32x4){0.f, 0.f, 0.f, 0.f};
        #pragma unroll
        for (int ksi = 0; ksi < 3; ++ksi) {
            short8v ao = *(const short8v*)(os + (mt * 16 + li) * 104 + ksi * 32 + 8 * gq);
            short8v bw = *(const short8v*)(wprj + (nt * 16 + li) * 96 + ksi * 32 + 8 * gq);
            acc = __builtin_amdgcn_mfma_f32_16x16x32_bf16(ao, bw, acc, 0, 0, 0);
        }
        int o = nt * 16 + li;
        float bo = projb[o];
        #pragma unroll
        for (int r = 0; r < 4; ++r) {
            int token = mt * 16 + 4 * gq + r;
            if (token < 72) {
                int th = token / 12, tw = token % 12;
                int hr = nwh * WH_ + th, wr = nww * WW_ + tw;
                int ho = SHIFT ? (hr + SH_) % HH : hr;
                int wo = SHIFT ? (wr + SW_) % WWID : wr;
                X[(((long)b * HH + ho) * WWID + wo) * CC + o] += acc[r] + bo;
            }
        }
    }
}

// ---------------- fused LN2 + MFMA MLP (unchanged, validated) ----------------
__global__ __launch_bounds__(256, 4) void k_mlp_mfma(float* __restrict__ X,
        const float* __restrict__ g, const float* __restrict__ bta,
        const unsigned short* __restrict__ w1f, const float* __restrict__ b1v,
        const unsigned short* __restrict__ w2f, const float* __restrict__ b2v) {
    __shared__ __align__(16) unsigned short As[32 * 120];
    __shared__ __align__(16) unsigned short Hs[32 * 392];
    long tok0 = (long)blockIdx.x * 32;
    int tid = threadIdx.x;

    {
        int t = tid >> 3, p = tid & 7;
        const float* xr = X + (tok0 + t) * CC;
        float4 a = *(const float4*)(xr + p * 4);
        float4 b = *(const float4*)(xr + p * 4 + 32);
        float4 c4 = *(const float4*)(xr + p * 4 + 64);
        float s  = a.x + a.y + a.z + a.w + b.x + b.y + b.z + b.w + c4.x + c4.y + c4.z + c4.w;
        float sq = a.x*a.x + a.y*a.y + a.z*a.z + a.w*a.w + b.x*b.x + b.y*b.y + b.z*b.z + b.w*b.w
                 + c4.x*c4.x + c4.y*c4.y + c4.z*c4.z + c4.w*c4.w;
        #pragma unroll
        for (int off = 1; off < 8; off <<= 1) {
            s  += __shfl_xor(s, off);
            sq += __shfl_xor(sq, off);
        }
        float mean = s * (1.f / CC);
        float var = sq * (1.f / CC) - mean * mean;
        float rs = rsqrtf(var + 1e-5f);
        float4 g0 = *(const float4*)(g + p * 4);
        float4 g1 = *(const float4*)(g + p * 4 + 32);
        float4 g2 = *(const float4*)(g + p * 4 + 64);
        float4 t0 = *(const float4*)(bta + p * 4);
        float4 t1 = *(const float4*)(bta + p * 4 + 32);
        float4 t2 = *(const float4*)(bta + p * 4 + 64);
        unsigned short* arow = As + t * 120;
        arow[p*4+0]  = pk_bf16((a.x - mean) * rs * g0.x + t0.x);
        arow[p*4+1]  = pk_bf16((a.y - mean) * rs * g0.y + t0.y);
        arow[p*4+2]  = pk_bf16((a.z - mean) * rs * g0.z + t0.z);
        arow[p*4+3]  = pk_bf16((a.w - mean) * rs * g0.w + t0.w);
        arow[p*4+32] = pk_bf16((b.x - mean) * rs * g1.x + t1.x);
        arow[p*4+33] = pk_bf16((b.y - mean) * rs * g1.y + t1.y);
        arow[p*4+34] = pk_bf16((b.z - mean) * rs * g1.z + t1.z);
        arow[p*4+35] = pk_bf16((b.w - mean) * rs * g1.w + t1.w);
        arow[p*4+64] = pk_bf16((c4.x - mean) * rs * g2.x + t2.x);
        arow[p*4+65] = pk_bf16((c4.y - mean) * rs * g2.y + t2.y);
        arow[p*4+66] = pk_bf16((c4.z - mean) * rs * g2.z + t2.z);
        arow[p*4+67] = pk_bf16((c4.w - mean) * rs * g2.w + t2.w);
    }
    __syncthreads();

    int w = tid >> 6, lane = tid & 63;
    int wm = w & 1;
    int row = wm * 16 + (lane & 15);
    int kbase = 8 * (lane >> 4);

    {
        int wnh = w >> 1;
        short8v afr[3];
        #pragma unroll
        for (int ks = 0; ks < 3; ++ks)
            afr[ks] = *(const short8v*)(As + row * 120 + ks * 32 + kbase);
        f32x4 acc[12];
        #pragma unroll
        for (int j = 0; j < 12; ++j) acc[j] = (f32x4){0.f, 0.f, 0.f, 0.f};
        const short8v* wb = (const short8v*)w1f;
        #pragma unroll
        for (int j = 0; j < 12; ++j) {
            int nt = wnh * 12 + j;
            #pragma unroll
            for (int ks = 0; ks < 3; ++ks) {
                short8v bfr = wb[(ks * 24 + nt) * 64 + lane];
                acc[j] = __builtin_amdgcn_mfma_f32_16x16x32_bf16(afr[ks], bfr, acc[j], 0, 0, 0);
            }
        }
        #pragma unroll
        for (int j = 0; j < 12; ++j) {
            int n = (wnh * 12 + j) * 16 + (lane & 15);
            float bb = b1v[n];
            #pragma unroll
            for (int r = 0; r < 4; ++r) {
                float s = acc[j][r] + bb;
                float z = s + 0.044715f * s * s * s;
                float gl = s / (1.f + __expf(-1.5957691216057308f * z));
                Hs[(wm * 16 + 4 * (lane >> 4) + r) * 392 + n] = pk_bf16(gl);
            }
        }
    }
    __syncthreads();

    {
        int wnt0 = (w >> 1) * 3;
        f32x4 acc2[3];
        #pragma unroll
        for (int j = 0; j < 3; ++j) acc2[j] = (f32x4){0.f, 0.f, 0.f, 0.f};
        const short8v* wb2 = (const short8v*)w2f;
        #pragma unroll
        for (int ks = 0; ks < 12; ++ks) {
            short8v a2 = *(const short8v*)(Hs + row * 392 + ks * 32 + kbase);
            #pragma unroll
            for (int j = 0; j < 3; ++j) {
                short8v bfr = wb2[(ks * 6 + wnt0 + j) * 64 + lane];
                acc2[j] = __builtin_amdgcn_mfma_f32_16x16x32_bf16(a2, bfr, acc2[j], 0, 0, 0);
            }
        }
        #pragma unroll
        for (int j = 0; j < 3; ++j) {
            int n = (wnt0 + j) * 16 + (lane & 15);
            float bb = b2v[n];
            #pragma unroll
            for (int r = 0; r < 4; ++r) {
                long tok = tok0 + wm * 16 + 4 * (lane >> 4) + r;
                X[tok * CC + n] += acc2[j][r] + bb;
            }
        }
    }
}

extern "C" void kernel_launch(void* const* d_in, const int* in_sizes, int n_in,
                              void* d_out, int out_size, void* d_ws, size_t ws_size,
                              hipStream_t stream) {
    const float* x     = (const float*)d_in[0];
    const float* g1    = (const float*)d_in[1];
    const float* b1    = (const float*)d_in[2];
    const float* qkvw  = (const float*)d_in[3];
    const float* qkvb  = (const float*)d_in[4];
    const float* projw = (const float*)d_in[5];
    const float* projb = (const float*)d_in[6];
    const float* rpb   = (const float*)d_in[7];
    const float* g2    = (const float*)d_in[8];
    const float* b2    = (const float*)d_in[9];
    const float* f1w   = (const float*)d_in[10];
    const float* f1b   = (const float*)d_in[11];
    const float* f2w   = (const float*)d_in[12];
    const float* f2b   = (const float*)d_in[13];

    float* X = (float*)d_ws;                                  // 51.4 MB
    unsigned short* wbf = (unsigned short*)(X + (long)BB * HH * WWID * CC);

    const int ntok = BB * HH * WWID;

    k_pad2<<<BB * HH * 12 * 3, 256, 0, stream>>>(x, X);
    k_wprep<<<864, 256, 0, stream>>>(f1w, f2w, qkvw, projw, wbf);

    for (int i = 0; i < 2; ++i) {
        const unsigned short* wqkv_bf = wbf + 147456 + (long)i * 27648;
        const unsigned short* wprj_bf = wbf + 202752 + (long)i * 9216;
        if (i == 0) {
            k_attn<0><<<BB * NWIN, 512, 0, stream>>>(X, g1, b1,
                wqkv_bf, qkvb, wprj_bf, projb, rpb);
        } else {
            k_attn<1><<<BB * NWIN, 512, 0, stream>>>(X, g1 + CC, b1 + CC,
                wqkv_bf, qkvb + 3 * CC, wprj_bf, projb + CC, rpb + 253 * NHD);
        }
        k_mlp_mfma<<<ntok / 32, 256, 0, stream>>>(X,
            g2 + i * CC, b2 + i * CC,
            wbf + (long)i * 36864, f1b + i * 4 * CC,
            wbf + 73728 + (long)i * 36864, f2b + i * CC);
    }

    k_crop2<<<BB * LAT_ * 12 * 3, 256, 0, stream>>>(X, (float*)d_out);
}

// Round 7
// 346.443 us; speedup vs baseline: 20.7814x; 1.1903x over previous
//
#include <hip/hip_runtime.h>
#include <math.h>

// ---- problem constants ----
#define BB    2
#define CC    96
#define NHD   4
#define HDIM  24
#define LAT_  181
#define LON_  360
#define PT_   2
#define HH    186
#define WWID  360
#define WH_   6
#define WW_   12
#define NTOK  72
#define SH_   3
#define SW_   6
#define NWH_  31
#define NWW_  30
#define NWIN  930
#define SCALE_ 0.20412414523193154f   // 24^-0.5

typedef __attribute__((ext_vector_type(8))) short short8v;
typedef __attribute__((ext_vector_type(4))) float f32x4;

__device__ __forceinline__ unsigned short pk_bf16(float x) {
    unsigned u = __float_as_uint(x);
    unsigned r = (u + 0x7fffu + ((u >> 16) & 1u)) >> 16;   // RNE
    return (unsigned short)r;
}
__device__ __forceinline__ uint2 pk4(float a, float b, float c, float d) {
    uint2 r;
    r.x = (unsigned)pk_bf16(a) | ((unsigned)pk_bf16(b) << 16);
    r.y = (unsigned)pk_bf16(c) | ((unsigned)pk_bf16(d) << 16);
    return r;
}

// ---------------- pad + NCHW->NHWC via LDS tile transpose ----------------
__global__ __launch_bounds__(256) void k_pad2(const float* __restrict__ in, float* __restrict__ X) {
    int bid = blockIdx.x;
    int ct = bid % 3; bid /= 3;
    int wt = bid % 12; bid /= 12;
    int h = bid % HH; int b = bid / HH;
    int lat = h - PT_;
    int tx = threadIdx.x & 31, ty = threadIdx.x >> 5;
    __shared__ float tile[32][33];
    if (lat >= 0 && lat < LAT_) {
        int w = wt * 32 + tx;
        #pragma unroll
        for (int i = 0; i < 4; ++i) {
            int c = ct * 32 + ty + 8 * i;
            float v = 0.f;
            if (w < WWID) v = in[((long)(b * CC + c)) * (LAT_ * LON_) + lat * LON_ + w];
            tile[ty + 8 * i][tx] = v;
        }
    } else {
        #pragma unroll
        for (int i = 0; i < 4; ++i) tile[ty + 8 * i][tx] = 0.f;
    }
    __syncthreads();
    #pragma unroll
    for (int i = 0; i < 4; ++i) {
        int w = wt * 32 + ty + 8 * i;
        if (w < WWID)
            X[(((long)(b * HH + h)) * WWID + w) * CC + ct * 32 + tx] = tile[tx][ty + 8 * i];
    }
}

// ---------------- crop + NHWC->NCHW via LDS tile transpose ----------------
__global__ __launch_bounds__(256) void k_crop2(const float* __restrict__ X, float* __restrict__ out) {
    int bid = blockIdx.x;
    int ct = bid % 3; bid /= 3;
    int wt = bid % 12; bid /= 12;
    int lat = bid % LAT_; int b = bid / LAT_;
    int h = lat + PT_;
    int tx = threadIdx.x & 31, ty = threadIdx.x >> 5;
    __shared__ float tile[32][33];
    #pragma unroll
    for (int i = 0; i < 4; ++i) {
        int w = wt * 32 + ty + 8 * i;
        if (w < WWID)
            tile[ty + 8 * i][tx] = X[(((long)(b * HH + h)) * WWID + w) * CC + ct * 32 + tx];
    }
    __syncthreads();
    {
        int w = wt * 32 + tx;
        if (w < WWID) {
            #pragma unroll
            for (int i = 0; i < 4; ++i) {
                int c = ct * 32 + ty + 8 * i;
                out[((long)(b * CC + c)) * (LAT_ * LON_) + lat * LON_ + w] = tile[tx][ty + 8 * i];
            }
        }
    }
}

// ---------------- weight prep + bias/mask tables ----------------
// shorts: [0) w1f 2x36864 | [73728) w2f 2x36864 | [147456) qkvw_bf 2x27648 | [202752) projw_bf 2x9216
// floats (after 221184 shorts): bias[2][4 types][4 heads][80][80]
__global__ void k_wprep(const float* __restrict__ f1w, const float* __restrict__ f2w,
                        const float* __restrict__ qkvw, const float* __restrict__ projw,
                        const float* __restrict__ rpb,
                        unsigned short* __restrict__ wbf, float* __restrict__ biasg) {
    int id = blockIdx.x * 256 + threadIdx.x;   // 425984 total
    if (id < 73728) {
        int layer = id / 36864, rem = id % 36864;
        int ks = rem / 12288, r2 = rem % 12288;
        int nt = r2 / 512, r3 = r2 % 512;
        int lane = r3 / 8, e = r3 % 8;
        int o = nt * 16 + (lane & 15);
        int c = ks * 32 + 8 * (lane >> 4) + e;
        wbf[(long)layer * 36864 + rem] = pk_bf16(f1w[((long)layer * 384 + o) * 96 + c]);
    } else if (id < 147456) {
        int id2 = id - 73728;
        int layer = id2 / 36864, rem = id2 % 36864;
        int ks = rem / 3072, r2 = rem % 3072;
        int nt = r2 / 512, r3 = r2 % 512;
        int lane = r3 / 8, e = r3 % 8;
        int o = nt * 16 + (lane & 15);
        int c = ks * 32 + 8 * (lane >> 4) + e;
        wbf[73728 + (long)layer * 36864 + rem] = pk_bf16(f2w[((long)layer * 96 + o) * 384 + c]);
    } else if (id < 202752) {
        wbf[id] = pk_bf16(qkvw[id - 147456]);
    } else if (id < 221184) {
        wbf[id] = pk_bf16(projw[id - 202752]);
    } else {
        int id2 = id - 221184;                 // 0..204799
        int layer = id2 / 102400, r = id2 % 102400;
        int type = r / 25600; r %= 25600;
        int h = r / 6400; r %= 6400;
        int i = r / 80, j = r % 80;
        float v;
        if (i >= 72 || j >= 72) {
            v = -10000.f;
        } else {
            int thi = i / 12, twi = i % 12, thj = j / 12, twj = j % 12;
            int ridx = (thi - thj + 5) * 23 + (twi - twj + 11);
            v = rpb[(layer * 253 + ridx) * 4 + h];
            if (layer == 1) {
                int eh = type & 1, ew = type >> 1;
                int ri = (eh ? (thi < 3 ? 1 : 2) * 3 : 0) + (ew ? (twi < 6 ? 1 : 2) : 0);
                int rj = (eh ? (thj < 3 ? 1 : 2) * 3 : 0) + (ew ? (twj < 6 ? 1 : 2) : 0);
                if (ri != rj) v -= 100.f;
            }
        }
        biasg[id2] = v;
    }
}

// ---------------- fused LN1 + MFMA window attention + proj + residual ----------------
// LDS (125184 B):
//   [0)       As [80][104] bf16  | ps [4][80][104] bf16 (alias)
//   [66560)   qs [4][80][24] bf16 | os [80][104] bf16 (alias)
//   [83200)   ks [4][80][24] bf16
//   [98560)   vt [4][32][104] bf16
template <int SHIFT>
__global__ __launch_bounds__(1024, 4) void k_attn(float* __restrict__ X,
        const float* __restrict__ gg, const float* __restrict__ bb,
        const unsigned short* __restrict__ wqkv, const float* __restrict__ qkvb,
        const unsigned short* __restrict__ wprj, const float* __restrict__ projb,
        const float* __restrict__ biasT) {
    __shared__ __align__(16) unsigned char smem[125184];
    unsigned short* As  = (unsigned short*)smem;
    unsigned short* ps  = (unsigned short*)smem;
    unsigned short* qs  = (unsigned short*)(smem + 66560);
    unsigned short* os  = (unsigned short*)(smem + 66560);
    unsigned short* ks  = (unsigned short*)(smem + 83200);
    unsigned short* vt  = (unsigned short*)(smem + 98560);

    int bid = blockIdx.x;
    int b = bid / NWIN, wi = bid % NWIN;
    int nwh = wi / NWW_, nww = wi % NWW_;
    int tid = threadIdx.x;
    int wv = tid >> 6, lane = tid & 63;
    int li = lane & 15, gq = lane >> 4;

    int type = SHIFT ? ((nwh == 30 ? 1 : 0) | (nww == 29 ? 2 : 0)) : 0;
    const float* bias_t = biasT + type * 25600;

    // zero-init pad regions read by MFMA
    {
        unsigned* vz = (unsigned*)vt;
        for (int idx = tid; idx < 6656; idx += 1024) vz[idx] = 0u;
        unsigned* az = (unsigned*)(As + 72 * 104);
        for (int idx = tid; idx < 416; idx += 1024) az[idx] = 0u;
    }

    // ---- phase 0: gather window + LN1 -> As (bf16); 8 lanes per token ----
    {
        int sub = lane >> 3, p = lane & 7;
        int t = wv * 8 + sub;
        if (t < 72) {
            int th = t / 12, tw = t % 12;
            int hr = nwh * WH_ + th, wr = nww * WW_ + tw;
            int ho = SHIFT ? (hr + SH_) % HH : hr;
            int wo = SHIFT ? (wr + SW_) % WWID : wr;
            const float* xr = X + (((long)b * HH + ho) * WWID + wo) * CC;
            float4 a  = *(const float4*)(xr + p * 4);
            float4 c4 = *(const float4*)(xr + p * 4 + 32);
            float4 e4 = *(const float4*)(xr + p * 4 + 64);
            float s  = a.x + a.y + a.z + a.w + c4.x + c4.y + c4.z + c4.w + e4.x + e4.y + e4.z + e4.w;
            float sq = a.x*a.x + a.y*a.y + a.z*a.z + a.w*a.w + c4.x*c4.x + c4.y*c4.y + c4.z*c4.z + c4.w*c4.w
                     + e4.x*e4.x + e4.y*e4.y + e4.z*e4.z + e4.w*e4.w;
            #pragma unroll
            for (int off = 1; off < 8; off <<= 1) {
                s  += __shfl_xor(s, off);
                sq += __shfl_xor(sq, off);
            }
            float mean = s * (1.f / CC);
            float var = sq * (1.f / CC) - mean * mean;
            float rs = rsqrtf(var + 1e-5f);
            float4 g0 = *(const float4*)(gg + p * 4);
            float4 g1v = *(const float4*)(gg + p * 4 + 32);
            float4 g2v = *(const float4*)(gg + p * 4 + 64);
            float4 t0 = *(const float4*)(bb + p * 4);
            float4 t1 = *(const float4*)(bb + p * 4 + 32);
            float4 t2 = *(const float4*)(bb + p * 4 + 64);
            *(uint2*)(As + t * 104 + p * 4) =
                pk4((a.x - mean) * rs * g0.x + t0.x, (a.y - mean) * rs * g0.y + t0.y,
                    (a.z - mean) * rs * g0.z + t0.z, (a.w - mean) * rs * g0.w + t0.w);
            *(uint2*)(As + t * 104 + p * 4 + 32) =
                pk4((c4.x - mean) * rs * g1v.x + t1.x, (c4.y - mean) * rs * g1v.y + t1.y,
                    (c4.z - mean) * rs * g1v.z + t1.z, (c4.w - mean) * rs * g1v.w + t1.w);
            *(uint2*)(As + t * 104 + p * 4 + 64) =
                pk4((e4.x - mean) * rs * g2v.x + t2.x, (e4.y - mean) * rs * g2v.y + t2.y,
                    (e4.z - mean) * rs * g2v.z + t2.z, (e4.w - mean) * rs * g2v.w + t2.w);
        }
    }
    __syncthreads();

    // ---- QKV: C[o][token] = Wqkv @ Y^T ----
    for (int mt = wv; mt < 18; mt += 16) {
        short8v aw[3];
        #pragma unroll
        for (int ksi = 0; ksi < 3; ++ksi)
            aw[ksi] = *(const short8v*)(wqkv + (mt * 16 + li) * 96 + ksi * 32 + 8 * gq);
        float bias4[4];
        #pragma unroll
        for (int r = 0; r < 4; ++r) bias4[r] = qkvb[mt * 16 + 4 * gq + r];
        f32x4 acc[5];
        #pragma unroll
        for (int nt = 0; nt < 5; ++nt) acc[nt] = (f32x4){0.f, 0.f, 0.f, 0.f};
        #pragma unroll
        for (int nt = 0; nt < 5; ++nt)
            #pragma unroll
            for (int ksi = 0; ksi < 3; ++ksi) {
                short8v by = *(const short8v*)(As + (nt * 16 + li) * 104 + ksi * 32 + 8 * gq);
                acc[nt] = __builtin_amdgcn_mfma_f32_16x16x32_bf16(aw[ksi], by, acc[nt], 0, 0, 0);
            }
        int which = mt / 6, mtl = mt % 6;
        int oo0 = mtl * 16 + 4 * gq;
        int h = oo0 / 24, d0 = oo0 % 24;
        #pragma unroll
        for (int nt = 0; nt < 5; ++nt) {
            int token = nt * 16 + li;
            if (which == 2) {
                #pragma unroll
                for (int r = 0; r < 4; ++r)
                    vt[(h * 32 + d0 + r) * 104 + token] = pk_bf16(acc[nt][r] + bias4[r]);
            } else {
                float v0 = acc[nt][0] + bias4[0], v1 = acc[nt][1] + bias4[1];
                float v2 = acc[nt][2] + bias4[2], v3 = acc[nt][3] + bias4[3];
                if (which == 0) { v0 *= SCALE_; v1 *= SCALE_; v2 *= SCALE_; v3 *= SCALE_; }
                unsigned short* dst = (which == 0 ? qs : ks) + (h * 80 + token) * 24 + d0;
                *(uint2*)dst = pk4(v0, v1, v2, v3);
            }
        }
    }
    __syncthreads();

    // ---- S^T = K @ Q^T + table bias + softmax -> ps[i][j] ----
    for (int u = wv; u < 20; u += 16) {
        int h = u / 5, nt = u % 5;
        int i = nt * 16 + li;
        *(uint2*)(ps + (h * 80 + i) * 104 + 80 + 4 * gq) = (uint2){0u, 0u};
        short8v bq = {0,0,0,0,0,0,0,0};
        if (gq < 3) bq = *(const short8v*)(qs + (h * 80 + i) * 24 + 8 * gq);
        const float* brow = bias_t + (h * 80 + i) * 80;
        float p[20];
        float sum = 0.f;
        #pragma unroll
        for (int mt = 0; mt < 5; ++mt) {
            short8v ak = {0,0,0,0,0,0,0,0};
            if (gq < 3) ak = *(const short8v*)(ks + (h * 80 + mt * 16 + li) * 24 + 8 * gq);
            f32x4 ct = __builtin_amdgcn_mfma_f32_16x16x32_bf16(ak, bq, (f32x4){0.f,0.f,0.f,0.f}, 0, 0, 0);
            float4 bv = *(const float4*)(brow + mt * 16 + 4 * gq);
            p[mt*4+0] = __expf(ct[0] + bv.x);
            p[mt*4+1] = __expf(ct[1] + bv.y);
            p[mt*4+2] = __expf(ct[2] + bv.z);
            p[mt*4+3] = __expf(ct[3] + bv.w);
            sum += p[mt*4+0] + p[mt*4+1] + p[mt*4+2] + p[mt*4+3];
        }
        sum += __shfl_xor(sum, 16);
        sum += __shfl_xor(sum, 32);
        float inv = sum > 0.f ? 1.f / sum : 0.f;
        #pragma unroll
        for (int mt = 0; mt < 5; ++mt)
            *(uint2*)(ps + (h * 80 + i) * 104 + mt * 16 + 4 * gq) =
                pk4(p[mt*4+0] * inv, p[mt*4+1] * inv, p[mt*4+2] * inv, p[mt*4+3] * inv);
    }
    __syncthreads();

    // ---- PV: O[i][d] = P @ V -> os[i][h*24+d] ----
    for (int u = wv; u < 40; u += 16) {
        int h = u / 10, rm = u % 10, mt = rm >> 1, nt2 = rm & 1;
        f32x4 acc = (f32x4){0.f, 0.f, 0.f, 0.f};
        #pragma unroll
        for (int ksi = 0; ksi < 3; ++ksi) {
            short8v ap = *(const short8v*)(ps + (h * 80 + mt * 16 + li) * 104 + ksi * 32 + 8 * gq);
            short8v bv = *(const short8v*)(vt + (h * 32 + nt2 * 16 + li) * 104 + ksi * 32 + 8 * gq);
            acc = __builtin_amdgcn_mfma_f32_16x16x32_bf16(ap, bv, acc, 0, 0, 0);
        }
        int d = nt2 * 16 + li;
        if (d < 24) {
            #pragma unroll
            for (int r = 0; r < 4; ++r)
                os[(mt * 16 + 4 * gq + r) * 104 + h * 24 + d] = pk_bf16(acc[r]);
        }
    }
    __syncthreads();

    // ---- proj + residual scatter ----
    for (int u = wv; u < 30; u += 16) {
        int mt = u / 6, nt = u % 6;
        f32x4 acc = (f32x4){0.f, 0.f, 0.f, 0.f};
        #pragma unroll
        for (int ksi = 0; ksi < 3; ++ksi) {
            short8v ao = *(const short8v*)(os + (mt * 16 + li) * 104 + ksi * 32 + 8 * gq);
            short8v bw = *(const short8v*)(wprj + (nt * 16 + li) * 96 + ksi * 32 + 8 * gq);
            acc = __builtin_amdgcn_mfma_f32_16x16x32_bf16(ao, bw, acc, 0, 0, 0);
        }
        int o = nt * 16 + li;
        float bo = projb[o];
        #pragma unroll
        for (int r = 0; r < 4; ++r) {
            int token = mt * 16 + 4 * gq + r;
            if (token < 72) {
                int th = token / 12, tw = token % 12;
                int hr = nwh * WH_ + th, wr = nww * WW_ + tw;
                int ho = SHIFT ? (hr + SH_) % HH : hr;
                int wo = SHIFT ? (wr + SW_) % WWID : wr;
                X[(((long)b * HH + ho) * WWID + wo) * CC + o] += acc[r] + bo;
            }
        }
    }
}

// ---------------- fused LN2 + MFMA MLP (unchanged, validated) ----------------
__global__ __launch_bounds__(256, 4) void k_mlp_mfma(float* __restrict__ X,
        const float* __restrict__ g, const float* __restrict__ bta,
        const unsigned short* __restrict__ w1f, const float* __restrict__ b1v,
        const unsigned short* __restrict__ w2f, const float* __restrict__ b2v) {
    __shared__ __align__(16) unsigned short As[32 * 120];
    __shared__ __align__(16) unsigned short Hs[32 * 392];
    long tok0 = (long)blockIdx.x * 32;
    int tid = threadIdx.x;

    {
        int t = tid >> 3, p = tid & 7;
        const float* xr = X + (tok0 + t) * CC;
        float4 a = *(const float4*)(xr + p * 4);
        float4 b = *(const float4*)(xr + p * 4 + 32);
        float4 c4 = *(const float4*)(xr + p * 4 + 64);
        float s  = a.x + a.y + a.z + a.w + b.x + b.y + b.z + b.w + c4.x + c4.y + c4.z + c4.w;
        float sq = a.x*a.x + a.y*a.y + a.z*a.z + a.w*a.w + b.x*b.x + b.y*b.y + b.z*b.z + b.w*b.w
                 + c4.x*c4.x + c4.y*c4.y + c4.z*c4.z + c4.w*c4.w;
        #pragma unroll
        for (int off = 1; off < 8; off <<= 1) {
            s  += __shfl_xor(s, off);
            sq += __shfl_xor(sq, off);
        }
        float mean = s * (1.f / CC);
        float var = sq * (1.f / CC) - mean * mean;
        float rs = rsqrtf(var + 1e-5f);
        float4 g0 = *(const float4*)(g + p * 4);
        float4 g1 = *(const float4*)(g + p * 4 + 32);
        float4 g2 = *(const float4*)(g + p * 4 + 64);
        float4 t0 = *(const float4*)(bta + p * 4);
        float4 t1 = *(const float4*)(bta + p * 4 + 32);
        float4 t2 = *(const float4*)(bta + p * 4 + 64);
        unsigned short* arow = As + t * 120;
        arow[p*4+0]  = pk_bf16((a.x - mean) * rs * g0.x + t0.x);
        arow[p*4+1]  = pk_bf16((a.y - mean) * rs * g0.y + t0.y);
        arow[p*4+2]  = pk_bf16((a.z - mean) * rs * g0.z + t0.z);
        arow[p*4+3]  = pk_bf16((a.w - mean) * rs * g0.w + t0.w);
        arow[p*4+32] = pk_bf16((b.x - mean) * rs * g1.x + t1.x);
        arow[p*4+33] = pk_bf16((b.y - mean) * rs * g1.y + t1.y);
        arow[p*4+34] = pk_bf16((b.z - mean) * rs * g1.z + t1.z);
        arow[p*4+35] = pk_bf16((b.w - mean) * rs * g1.w + t1.w);
        arow[p*4+64] = pk_bf16((c4.x - mean) * rs * g2.x + t2.x);
        arow[p*4+65] = pk_bf16((c4.y - mean) * rs * g2.y + t2.y);
        arow[p*4+66] = pk_bf16((c4.z - mean) * rs * g2.z + t2.z);
        arow[p*4+67] = pk_bf16((c4.w - mean) * rs * g2.w + t2.w);
    }
    __syncthreads();

    int w = tid >> 6, lane = tid & 63;
    int wm = w & 1;
    int row = wm * 16 + (lane & 15);
    int kbase = 8 * (lane >> 4);

    {
        int wnh = w >> 1;
        short8v afr[3];
        #pragma unroll
        for (int ks = 0; ks < 3; ++ks)
            afr[ks] = *(const short8v*)(As + row * 120 + ks * 32 + kbase);
        f32x4 acc[12];
        #pragma unroll
        for (int j = 0; j < 12; ++j) acc[j] = (f32x4){0.f, 0.f, 0.f, 0.f};
        const short8v* wb = (const short8v*)w1f;
        #pragma unroll
        for (int j = 0; j < 12; ++j) {
            int nt = wnh * 12 + j;
            #pragma unroll
            for (int ks = 0; ks < 3; ++ks) {
                short8v bfr = wb[(ks * 24 + nt) * 64 + lane];
                acc[j] = __builtin_amdgcn_mfma_f32_16x16x32_bf16(afr[ks], bfr, acc[j], 0, 0, 0);
            }
        }
        #pragma unroll
        for (int j = 0; j < 12; ++j) {
            int n = (wnh * 12 + j) * 16 + (lane & 15);
            float bb = b1v[n];
            #pragma unroll
            for (int r = 0; r < 4; ++r) {
                float s = acc[j][r] + bb;
                float z = s + 0.044715f * s * s * s;
                float gl = s / (1.f + __expf(-1.5957691216057308f * z));
                Hs[(wm * 16 + 4 * (lane >> 4) + r) * 392 + n] = pk_bf16(gl);
            }
        }
    }
    __syncthreads();

    {
        int wnt0 = (w >> 1) * 3;
        f32x4 acc2[3];
        #pragma unroll
        for (int j = 0; j < 3; ++j) acc2[j] = (f32x4){0.f, 0.f, 0.f, 0.f};
        const short8v* wb2 = (const short8v*)w2f;
        #pragma unroll
        for (int ks = 0; ks < 12; ++ks) {
            short8v a2 = *(const short8v*)(Hs + row * 392 + ks * 32 + kbase);
            #pragma unroll
            for (int j = 0; j < 3; ++j) {
                short8v bfr = wb2[(ks * 6 + wnt0 + j) * 64 + lane];
                acc2[j] = __builtin_amdgcn_mfma_f32_16x16x32_bf16(a2, bfr, acc2[j], 0, 0, 0);
            }
        }
        #pragma unroll
        for (int j = 0; j < 3; ++j) {
            int n = (wnt0 + j) * 16 + (lane & 15);
            float bb = b2v[n];
            #pragma unroll
            for (int r = 0; r < 4; ++r) {
                long tok = tok0 + wm * 16 + 4 * (lane >> 4) + r;
                X[tok * CC + n] += acc2[j][r] + bb;
            }
        }
    }
}

extern "C" void kernel_launch(void* const* d_in, const int* in_sizes, int n_in,
                              void* d_out, int out_size, void* d_ws, size_t ws_size,
                              hipStream_t stream) {
    const float* x     = (const float*)d_in[0];
    const float* g1    = (const float*)d_in[1];
    const float* b1    = (const float*)d_in[2];
    const float* qkvw  = (const float*)d_in[3];
    const float* qkvb  = (const float*)d_in[4];
    const float* projw = (const float*)d_in[5];
    const float* projb = (const float*)d_in[6];
    const float* rpb   = (const float*)d_in[7];
    const float* g2    = (const float*)d_in[8];
    const float* b2    = (const float*)d_in[9];
    const float* f1w   = (const float*)d_in[10];
    const float* f1b   = (const float*)d_in[11];
    const float* f2w   = (const float*)d_in[12];
    const float* f2b   = (const float*)d_in[13];

    float* X = (float*)d_ws;                                  // 51.4 MB
    unsigned short* wbf = (unsigned short*)(X + (long)BB * HH * WWID * CC);
    float* biasg = (float*)(wbf + 221184);                    // 2 x 102400 f32

    const int ntok = BB * HH * WWID;

    k_pad2<<<BB * HH * 12 * 3, 256, 0, stream>>>(x, X);
    k_wprep<<<1664, 256, 0, stream>>>(f1w, f2w, qkvw, projw, rpb, wbf, biasg);

    for (int i = 0; i < 2; ++i) {
        const unsigned short* wqkv_bf = wbf + 147456 + (long)i * 27648;
        const unsigned short* wprj_bf = wbf + 202752 + (long)i * 9216;
        if (i == 0) {
            k_attn<0><<<BB * NWIN, 1024, 0, stream>>>(X, g1, b1,
                wqkv_bf, qkvb, wprj_bf, projb, biasg);
        } else {
            k_attn<1><<<BB * NWIN, 1024, 0, stream>>>(X, g1 + CC, b1 + CC,
                wqkv_bf, qkvb + 3 * CC, wprj_bf, projb + CC, biasg + 102400);
        }
        k_mlp_mfma<<<ntok / 32, 256, 0, stream>>>(X,
            g2 + i * CC, b2 + i * CC,
            wbf + (long)i * 36864, f1b + i * 4 * CC,
            wbf + 73728 + (long)i * 36864, f2b + i * CC);
    }

    k_crop2<<<BB * LAT_ * 12 * 3, 256, 0, stream>>>(X, (float*)d_out);
}

// Round 8
// 326.700 us; speedup vs baseline: 22.0372x; 1.0604x over previous
//
#include <hip/hip_runtime.h>
#include <hip/hip_bf16.h>
#include <math.h>

// ---- problem constants ----
#define BB    2
#define CC    96
#define NHD   4
#define HDIM  24
#define LAT_  181
#define LON_  360
#define PT_   2
#define HH    186
#define WWID  360
#define WH_   6
#define WW_   12
#define NTOK  72
#define SH_   3
#define SW_   6
#define NWH_  31
#define NWW_  30
#define NWIN  930
#define SCALE_ 0.20412414523193154f   // 24^-0.5

typedef __attribute__((ext_vector_type(8))) short short8v;
typedef __attribute__((ext_vector_type(4))) float f32x4;

__device__ __forceinline__ unsigned short pk_bf16(float x) {
    __hip_bfloat16 h = __float2bfloat16(x);          // RNE, v_cvt hw path
    union { __hip_bfloat16 b; unsigned short u; } cv; cv.b = h; return cv.u;
}
__device__ __forceinline__ uint2 pk4(float a, float b, float c, float d) {
    __hip_bfloat162 lo = __float22bfloat162_rn(make_float2(a, b));
    __hip_bfloat162 hi = __float22bfloat162_rn(make_float2(c, d));
    union { __hip_bfloat162 b; unsigned u; } c0, c1; c0.b = lo; c1.b = hi;
    uint2 r; r.x = c0.u; r.y = c1.u; return r;
}

// ---------------- pad + NCHW->NHWC via LDS tile transpose ----------------
__global__ __launch_bounds__(256) void k_pad2(const float* __restrict__ in, float* __restrict__ X) {
    int bid = blockIdx.x;
    int ct = bid % 3; bid /= 3;
    int wt = bid % 12; bid /= 12;
    int h = bid % HH; int b = bid / HH;
    int lat = h - PT_;
    int tx = threadIdx.x & 31, ty = threadIdx.x >> 5;
    __shared__ float tile[32][33];
    if (lat >= 0 && lat < LAT_) {
        int w = wt * 32 + tx;
        #pragma unroll
        for (int i = 0; i < 4; ++i) {
            int c = ct * 32 + ty + 8 * i;
            float v = 0.f;
            if (w < WWID) v = in[((long)(b * CC + c)) * (LAT_ * LON_) + lat * LON_ + w];
            tile[ty + 8 * i][tx] = v;
        }
    } else {
        #pragma unroll
        for (int i = 0; i < 4; ++i) tile[ty + 8 * i][tx] = 0.f;
    }
    __syncthreads();
    #pragma unroll
    for (int i = 0; i < 4; ++i) {
        int w = wt * 32 + ty + 8 * i;
        if (w < WWID)
            X[(((long)(b * HH + h)) * WWID + w) * CC + ct * 32 + tx] = tile[tx][ty + 8 * i];
    }
}

// ---------------- crop + NHWC->NCHW via LDS tile transpose ----------------
__global__ __launch_bounds__(256) void k_crop2(const float* __restrict__ X, float* __restrict__ out) {
    int bid = blockIdx.x;
    int ct = bid % 3; bid /= 3;
    int wt = bid % 12; bid /= 12;
    int lat = bid % LAT_; int b = bid / LAT_;
    int h = lat + PT_;
    int tx = threadIdx.x & 31, ty = threadIdx.x >> 5;
    __shared__ float tile[32][33];
    #pragma unroll
    for (int i = 0; i < 4; ++i) {
        int w = wt * 32 + ty + 8 * i;
        if (w < WWID)
            tile[ty + 8 * i][tx] = X[(((long)(b * HH + h)) * WWID + w) * CC + ct * 32 + tx];
    }
    __syncthreads();
    {
        int w = wt * 32 + tx;
        if (w < WWID) {
            #pragma unroll
            for (int i = 0; i < 4; ++i) {
                int c = ct * 32 + ty + 8 * i;
                out[((long)(b * CC + c)) * (LAT_ * LON_) + lat * LON_ + w] = tile[tx][ty + 8 * i];
            }
        }
    }
}

// ---------------- weight prep + bias/mask tables ----------------
__global__ void k_wprep(const float* __restrict__ f1w, const float* __restrict__ f2w,
                        const float* __restrict__ qkvw, const float* __restrict__ projw,
                        const float* __restrict__ rpb,
                        unsigned short* __restrict__ wbf, float* __restrict__ biasg) {
    int id = blockIdx.x * 256 + threadIdx.x;   // 425984 total
    if (id < 73728) {
        int layer = id / 36864, rem = id % 36864;
        int ks = rem / 12288, r2 = rem % 12288;
        int nt = r2 / 512, r3 = r2 % 512;
        int lane = r3 / 8, e = r3 % 8;
        int o = nt * 16 + (lane & 15);
        int c = ks * 32 + 8 * (lane >> 4) + e;
        wbf[(long)layer * 36864 + rem] = pk_bf16(f1w[((long)layer * 384 + o) * 96 + c]);
    } else if (id < 147456) {
        int id2 = id - 73728;
        int layer = id2 / 36864, rem = id2 % 36864;
        int ks = rem / 3072, r2 = rem % 3072;
        int nt = r2 / 512, r3 = r2 % 512;
        int lane = r3 / 8, e = r3 % 8;
        int o = nt * 16 + (lane & 15);
        int c = ks * 32 + 8 * (lane >> 4) + e;
        wbf[73728 + (long)layer * 36864 + rem] = pk_bf16(f2w[((long)layer * 96 + o) * 384 + c]);
    } else if (id < 202752) {
        wbf[id] = pk_bf16(qkvw[id - 147456]);
    } else if (id < 221184) {
        wbf[id] = pk_bf16(projw[id - 202752]);
    } else {
        int id2 = id - 221184;                 // 0..204799
        int layer = id2 / 102400, r = id2 % 102400;
        int type = r / 25600; r %= 25600;
        int h = r / 6400; r %= 6400;
        int i = r / 80, j = r % 80;
        float v;
        if (i >= 72 || j >= 72) {
            v = -10000.f;
        } else {
            int thi = i / 12, twi = i % 12, thj = j / 12, twj = j % 12;
            int ridx = (thi - thj + 5) * 23 + (twi - twj + 11);
            v = rpb[(layer * 253 + ridx) * 4 + h];
            if (layer == 1) {
                int eh = type & 1, ew = type >> 1;
                int ri = (eh ? (thi < 3 ? 1 : 2) * 3 : 0) + (ew ? (twi < 6 ? 1 : 2) : 0);
                int rj = (eh ? (thj < 3 ? 1 : 2) * 3 : 0) + (ew ? (twj < 6 ? 1 : 2) : 0);
                if (ri != rj) v -= 100.f;
            }
        }
        biasg[id2] = v;
    }
}

// ---------------- fused LN1 + MFMA window attention (fused S+PV) ----------------
// LDS (127232 B):
//   [0)       As [80][104] bf16 (LN'd window) | ps_w [16 waves][16][104] bf16 (alias, per-wave private)
//   [53248)   qs [4][80][24] bf16
//   [68608)   ks [4][80][24] bf16
//   [83968)   vt [4][32][104] bf16 (V transposed: [h][d][token])
//   [110592)  os [80][104] bf16
template <int SHIFT>
__global__ __launch_bounds__(1024, 4) void k_attn(float* __restrict__ X,
        const float* __restrict__ gg, const float* __restrict__ bb,
        const unsigned short* __restrict__ wqkv, const float* __restrict__ qkvb,
        const unsigned short* __restrict__ wprj, const float* __restrict__ projb,
        const float* __restrict__ biasT) {
    __shared__ __align__(16) unsigned char smem[127232];
    unsigned short* As  = (unsigned short*)smem;
    unsigned short* psw0= (unsigned short*)smem;             // per-wave scratch base (alias As)
    unsigned short* qs  = (unsigned short*)(smem + 53248);
    unsigned short* ks  = (unsigned short*)(smem + 68608);
    unsigned short* vt  = (unsigned short*)(smem + 83968);
    unsigned short* os  = (unsigned short*)(smem + 110592);

    int bid = blockIdx.x;
    int b = bid / NWIN, wi = bid % NWIN;
    int nwh = wi / NWW_, nww = wi % NWW_;
    int tid = threadIdx.x;
    int wv = tid >> 6, lane = tid & 63;
    int li = lane & 15, gq = lane >> 4;

    int type = SHIFT ? ((nwh == 30 ? 1 : 0) | (nww == 29 ? 2 : 0)) : 0;
    const float* bias_t = biasT + type * 25600;

    // zero-init pad regions read by MFMA
    {
        unsigned* vz = (unsigned*)vt;
        for (int idx = tid; idx < 6656; idx += 1024) vz[idx] = 0u;
        unsigned* az = (unsigned*)(As + 72 * 104);
        for (int idx = tid; idx < 416; idx += 1024) az[idx] = 0u;
    }

    // ---- phase 0: gather window + LN1 -> As (bf16); 8 lanes per token ----
    {
        int sub = lane >> 3, p = lane & 7;
        int t = wv * 8 + sub;
        if (t < 72) {
            int th = t / 12, tw = t % 12;
            int hr = nwh * WH_ + th, wr = nww * WW_ + tw;
            int ho = SHIFT ? (hr + SH_) % HH : hr;
            int wo = SHIFT ? (wr + SW_) % WWID : wr;
            const float* xr = X + (((long)b * HH + ho) * WWID + wo) * CC;
            float4 a  = *(const float4*)(xr + p * 4);
            float4 c4 = *(const float4*)(xr + p * 4 + 32);
            float4 e4 = *(const float4*)(xr + p * 4 + 64);
            float s  = a.x + a.y + a.z + a.w + c4.x + c4.y + c4.z + c4.w + e4.x + e4.y + e4.z + e4.w;
            float sq = a.x*a.x + a.y*a.y + a.z*a.z + a.w*a.w + c4.x*c4.x + c4.y*c4.y + c4.z*c4.z + c4.w*c4.w
                     + e4.x*e4.x + e4.y*e4.y + e4.z*e4.z + e4.w*e4.w;
            #pragma unroll
            for (int off = 1; off < 8; off <<= 1) {
                s  += __shfl_xor(s, off);
                sq += __shfl_xor(sq, off);
            }
            float mean = s * (1.f / CC);
            float var = sq * (1.f / CC) - mean * mean;
            float rs = rsqrtf(var + 1e-5f);
            float4 g0 = *(const float4*)(gg + p * 4);
            float4 g1v = *(const float4*)(gg + p * 4 + 32);
            float4 g2v = *(const float4*)(gg + p * 4 + 64);
            float4 t0 = *(const float4*)(bb + p * 4);
            float4 t1 = *(const float4*)(bb + p * 4 + 32);
            float4 t2 = *(const float4*)(bb + p * 4 + 64);
            *(uint2*)(As + t * 104 + p * 4) =
                pk4((a.x - mean) * rs * g0.x + t0.x, (a.y - mean) * rs * g0.y + t0.y,
                    (a.z - mean) * rs * g0.z + t0.z, (a.w - mean) * rs * g0.w + t0.w);
            *(uint2*)(As + t * 104 + p * 4 + 32) =
                pk4((c4.x - mean) * rs * g1v.x + t1.x, (c4.y - mean) * rs * g1v.y + t1.y,
                    (c4.z - mean) * rs * g1v.z + t1.z, (c4.w - mean) * rs * g1v.w + t1.w);
            *(uint2*)(As + t * 104 + p * 4 + 64) =
                pk4((e4.x - mean) * rs * g2v.x + t2.x, (e4.y - mean) * rs * g2v.y + t2.y,
                    (e4.z - mean) * rs * g2v.z + t2.z, (e4.w - mean) * rs * g2v.w + t2.w);
        }
    }
    __syncthreads();

    // ---- QKV: C[o][token] = Wqkv @ Y^T ----
    for (int mt = wv; mt < 18; mt += 16) {
        short8v aw[3];
        #pragma unroll
        for (int ksi = 0; ksi < 3; ++ksi)
            aw[ksi] = *(const short8v*)(wqkv + (mt * 16 + li) * 96 + ksi * 32 + 8 * gq);
        float bias4[4];
        #pragma unroll
        for (int r = 0; r < 4; ++r) bias4[r] = qkvb[mt * 16 + 4 * gq + r];
        f32x4 acc[5];
        #pragma unroll
        for (int nt = 0; nt < 5; ++nt) acc[nt] = (f32x4){0.f, 0.f, 0.f, 0.f};
        #pragma unroll
        for (int nt = 0; nt < 5; ++nt)
            #pragma unroll
            for (int ksi = 0; ksi < 3; ++ksi) {
                short8v by = *(const short8v*)(As + (nt * 16 + li) * 104 + ksi * 32 + 8 * gq);
                acc[nt] = __builtin_amdgcn_mfma_f32_16x16x32_bf16(aw[ksi], by, acc[nt], 0, 0, 0);
            }
        int which = mt / 6, mtl = mt % 6;
        int oo0 = mtl * 16 + 4 * gq;
        int h = oo0 / 24, d0 = oo0 % 24;
        #pragma unroll
        for (int nt = 0; nt < 5; ++nt) {
            int token = nt * 16 + li;
            if (which == 2) {
                #pragma unroll
                for (int r = 0; r < 4; ++r)
                    vt[(h * 32 + d0 + r) * 104 + token] = pk_bf16(acc[nt][r] + bias4[r]);
            } else {
                float v0 = acc[nt][0] + bias4[0], v1 = acc[nt][1] + bias4[1];
                float v2 = acc[nt][2] + bias4[2], v3 = acc[nt][3] + bias4[3];
                if (which == 0) { v0 *= SCALE_; v1 *= SCALE_; v2 *= SCALE_; v3 *= SCALE_; }
                unsigned short* dst = (which == 0 ? qs : ks) + (h * 80 + token) * 24 + d0;
                *(uint2*)dst = pk4(v0, v1, v2, v3);
            }
        }
    }
    __syncthreads();

    // ---- fused S + PV per wave: unit = (head h, i-strip nt) ----
    for (int u = wv; u < 20; u += 16) {
        int h = u / 5, nt = u % 5;
        unsigned short* psw = psw0 + (size_t)wv * (16 * 104);
        // zero j-pad cols [80,96) of this strip
        *(uint2*)(psw + li * 104 + 80 + 4 * gq) = (uint2){0u, 0u};
        short8v bq = {0,0,0,0,0,0,0,0};
        if (gq < 3) bq = *(const short8v*)(qs + (h * 80 + nt * 16 + li) * 24 + 8 * gq);
        const float* brow = bias_t + (h * 80 + nt * 16 + li) * 80;
        float p[20];
        float sum = 0.f;
        #pragma unroll
        for (int mt = 0; mt < 5; ++mt) {
            short8v ak = {0,0,0,0,0,0,0,0};
            if (gq < 3) ak = *(const short8v*)(ks + (h * 80 + mt * 16 + li) * 24 + 8 * gq);
            f32x4 ct = __builtin_amdgcn_mfma_f32_16x16x32_bf16(ak, bq, (f32x4){0.f,0.f,0.f,0.f}, 0, 0, 0);
            float4 bv = *(const float4*)(brow + mt * 16 + 4 * gq);
            p[mt*4+0] = __expf(ct[0] + bv.x);
            p[mt*4+1] = __expf(ct[1] + bv.y);
            p[mt*4+2] = __expf(ct[2] + bv.z);
            p[mt*4+3] = __expf(ct[3] + bv.w);
            sum += p[mt*4+0] + p[mt*4+1] + p[mt*4+2] + p[mt*4+3];
        }
        sum += __shfl_xor(sum, 16);
        sum += __shfl_xor(sum, 32);
        float inv = sum > 0.f ? 1.f / sum : 0.f;
        #pragma unroll
        for (int mt = 0; mt < 5; ++mt)
            *(uint2*)(psw + li * 104 + mt * 16 + 4 * gq) =
                pk4(p[mt*4+0] * inv, p[mt*4+1] * inv, p[mt*4+2] * inv, p[mt*4+3] * inv);
        // PV for this strip (same-wave LDS dependency -> lgkmcnt only, no barrier)
        #pragma unroll
        for (int nt2 = 0; nt2 < 2; ++nt2) {
            f32x4 acc = (f32x4){0.f, 0.f, 0.f, 0.f};
            #pragma unroll
            for (int ksi = 0; ksi < 3; ++ksi) {
                short8v ap = *(const short8v*)(psw + li * 104 + ksi * 32 + 8 * gq);
                short8v bv = *(const short8v*)(vt + (h * 32 + nt2 * 16 + li) * 104 + ksi * 32 + 8 * gq);
                acc = __builtin_amdgcn_mfma_f32_16x16x32_bf16(ap, bv, acc, 0, 0, 0);
            }
            int d = nt2 * 16 + li;
            if (d < 24) {
                #pragma unroll
                for (int r = 0; r < 4; ++r)
                    os[(nt * 16 + 4 * gq + r) * 104 + h * 24 + d] = pk_bf16(acc[r]);
            }
        }
    }
    __syncthreads();

    // ---- proj + residual scatter ----
    for (int u = wv; u < 30; u += 16) {
        int mt = u / 6, nt = u % 6;
        f32x4 acc = (f32x4){0.f, 0.f, 0.f, 0.f};
        #pragma unroll
        for (int ksi = 0; ksi < 3; ++ksi) {
            short8v ao = *(const short8v*)(os + (mt * 16 + li) * 104 + ksi * 32 + 8 * gq);
            short8v bw = *(const short8v*)(wprj + (nt * 16 + li) * 96 + ksi * 32 + 8 * gq);
            acc = __builtin_amdgcn_mfma_f32_16x16x32_bf16(ao, bw, acc, 0, 0, 0);
        }
        int o = nt * 16 + li;
        float bo = projb[o];
        #pragma unroll
        for (int r = 0; r < 4; ++r) {
            int token = mt * 16 + 4 * gq + r;
            if (token < 72) {
                int th = token / 12, tw = token % 12;
                int hr = nwh * WH_ + th, wr = nww * WW_ + tw;
                int ho = SHIFT ? (hr + SH_) % HH : hr;
                int wo = SHIFT ? (wr + SW_) % WWID : wr;
                X[(((long)b * HH + ho) * WWID + wo) * CC + o] += acc[r] + bo;
            }
        }
    }
}

// ---------------- fused LN2 + MFMA MLP (unchanged, validated) ----------------
__global__ __launch_bounds__(256, 4) void k_mlp_mfma(float* __restrict__ X,
        const float* __restrict__ g, const float* __restrict__ bta,
        const unsigned short* __restrict__ w1f, const float* __restrict__ b1v,
        const unsigned short* __restrict__ w2f, const float* __restrict__ b2v) {
    __shared__ __align__(16) unsigned short As[32 * 120];
    __shared__ __align__(16) unsigned short Hs[32 * 392];
    long tok0 = (long)blockIdx.x * 32;
    int tid = threadIdx.x;

    {
        int t = tid >> 3, p = tid & 7;
        const float* xr = X + (tok0 + t) * CC;
        float4 a = *(const float4*)(xr + p * 4);
        float4 b = *(const float4*)(xr + p * 4 + 32);
        float4 c4 = *(const float4*)(xr + p * 4 + 64);
        float s  = a.x + a.y + a.z + a.w + b.x + b.y + b.z + b.w + c4.x + c4.y + c4.z + c4.w;
        float sq = a.x*a.x + a.y*a.y + a.z*a.z + a.w*a.w + b.x*b.x + b.y*b.y + b.z*b.z + b.w*b.w
                 + c4.x*c4.x + c4.y*c4.y + c4.z*c4.z + c4.w*c4.w;
        #pragma unroll
        for (int off = 1; off < 8; off <<= 1) {
            s  += __shfl_xor(s, off);
            sq += __shfl_xor(sq, off);
        }
        float mean = s * (1.f / CC);
        float var = sq * (1.f / CC) - mean * mean;
        float rs = rsqrtf(var + 1e-5f);
        float4 g0 = *(const float4*)(g + p * 4);
        float4 g1 = *(const float4*)(g + p * 4 + 32);
        float4 g2 = *(const float4*)(g + p * 4 + 64);
        float4 t0 = *(const float4*)(bta + p * 4);
        float4 t1 = *(const float4*)(bta + p * 4 + 32);
        float4 t2 = *(const float4*)(bta + p * 4 + 64);
        unsigned short* arow = As + t * 120;
        *(uint2*)(arow + p * 4) =
            pk4((a.x - mean) * rs * g0.x + t0.x, (a.y - mean) * rs * g0.y + t0.y,
                (a.z - mean) * rs * g0.z + t0.z, (a.w - mean) * rs * g0.w + t0.w);
        *(uint2*)(arow + p * 4 + 32) =
            pk4((b.x - mean) * rs * g1.x + t1.x, (b.y - mean) * rs * g1.y + t1.y,
                (b.z - mean) * rs * g1.z + t1.z, (b.w - mean) * rs * g1.w + t1.w);
        *(uint2*)(arow + p * 4 + 64) =
            pk4((c4.x - mean) * rs * g2.x + t2.x, (c4.y - mean) * rs * g2.y + t2.y,
                (c4.z - mean) * rs * g2.z + t2.z, (c4.w - mean) * rs * g2.w + t2.w);
    }
    __syncthreads();

    int w = tid >> 6, lane = tid & 63;
    int wm = w & 1;
    int row = wm * 16 + (lane & 15);
    int kbase = 8 * (lane >> 4);

    {
        int wnh = w >> 1;
        short8v afr[3];
        #pragma unroll
        for (int ks = 0; ks < 3; ++ks)
            afr[ks] = *(const short8v*)(As + row * 120 + ks * 32 + kbase);
        f32x4 acc[12];
        #pragma unroll
        for (int j = 0; j < 12; ++j) acc[j] = (f32x4){0.f, 0.f, 0.f, 0.f};
        const short8v* wb = (const short8v*)w1f;
        #pragma unroll
        for (int j = 0; j < 12; ++j) {
            int nt = wnh * 12 + j;
            #pragma unroll
            for (int ks = 0; ks < 3; ++ks) {
                short8v bfr = wb[(ks * 24 + nt) * 64 + lane];
                acc[j] = __builtin_amdgcn_mfma_f32_16x16x32_bf16(afr[ks], bfr, acc[j], 0, 0, 0);
            }
        }
        #pragma unroll
        for (int j = 0; j < 12; ++j) {
            int n = (wnh * 12 + j) * 16 + (lane & 15);
            float bb = b1v[n];
            #pragma unroll
            for (int r = 0; r < 4; ++r) {
                float s = acc[j][r] + bb;
                float z = s + 0.044715f * s * s * s;
                float gl = s / (1.f + __expf(-1.5957691216057308f * z));
                Hs[(wm * 16 + 4 * (lane >> 4) + r) * 392 + n] = pk_bf16(gl);
            }
        }
    }
    __syncthreads();

    {
        int wnt0 = (w >> 1) * 3;
        f32x4 acc2[3];
        #pragma unroll
        for (int j = 0; j < 3; ++j) acc2[j] = (f32x4){0.f, 0.f, 0.f, 0.f};
        const short8v* wb2 = (const short8v*)w2f;
        #pragma unroll
        for (int ks = 0; ks < 12; ++ks) {
            short8v a2 = *(const short8v*)(Hs + row * 392 + ks * 32 + kbase);
            #pragma unroll
            for (int j = 0; j < 3; ++j) {
                short8v bfr = wb2[(ks * 6 + wnt0 + j) * 64 + lane];
                acc2[j] = __builtin_amdgcn_mfma_f32_16x16x32_bf16(a2, bfr, acc2[j], 0, 0, 0);
            }
        }
        #pragma unroll
        for (int j = 0; j < 3; ++j) {
            int n = (wnt0 + j) * 16 + (lane & 15);
            float bb = b2v[n];
            #pragma unroll
            for (int r = 0; r < 4; ++r) {
                long tok = tok0 + wm * 16 + 4 * (lane >> 4) + r;
                X[tok * CC + n] += acc2[j][r] + bb;
            }
        }
    }
}

extern "C" void kernel_launch(void* const* d_in, const int* in_sizes, int n_in,
                              void* d_out, int out_size, void* d_ws, size_t ws_size,
                              hipStream_t stream) {
    const float* x     = (const float*)d_in[0];
    const float* g1    = (const float*)d_in[1];
    const float* b1    = (const float*)d_in[2];
    const float* qkvw  = (const float*)d_in[3];
    const float* qkvb  = (const float*)d_in[4];
    const float* projw = (const float*)d_in[5];
    const float* projb = (const float*)d_in[6];
    const float* rpb   = (const float*)d_in[7];
    const float* g2    = (const float*)d_in[8];
    const float* b2    = (const float*)d_in[9];
    const float* f1w   = (const float*)d_in[10];
    const float* f1b   = (const float*)d_in[11];
    const float* f2w   = (const float*)d_in[12];
    const float* f2b   = (const float*)d_in[13];

    float* X = (float*)d_ws;                                  // 51.4 MB
    unsigned short* wbf = (unsigned short*)(X + (long)BB * HH * WWID * CC);
    float* biasg = (float*)(wbf + 221184);                    // 2 x 102400 f32

    const int ntok = BB * HH * WWID;

    k_pad2<<<BB * HH * 12 * 3, 256, 0, stream>>>(x, X);
    k_wprep<<<1664, 256, 0, stream>>>(f1w, f2w, qkvw, projw, rpb, wbf, biasg);

    for (int i = 0; i < 2; ++i) {
        const unsigned short* wqkv_bf = wbf + 147456 + (long)i * 27648;
        const unsigned short* wprj_bf = wbf + 202752 + (long)i * 9216;
        if (i == 0) {
            k_attn<0><<<BB * NWIN, 1024, 0, stream>>>(X, g1, b1,
                wqkv_bf, qkvb, wprj_bf, projb, biasg);
        } else {
            k_attn<1><<<BB * NWIN, 1024, 0, stream>>>(X, g1 + CC, b1 + CC,
                wqkv_bf, qkvb + 3 * CC, wprj_bf, projb + CC, biasg + 102400);
        }
        k_mlp_mfma<<<ntok / 32, 256, 0, stream>>>(X,
            g2 + i * CC, b2 + i * CC,
            wbf + (long)i * 36864, f1b + i * 4 * CC,
            wbf + 73728 + (long)i * 36864, f2b + i * CC);
    }

    k_crop2<<<BB * LAT_ * 12 * 3, 256, 0, stream>>>(X, (float*)d_out);
}